// Round 6
// baseline (559.844 us; speedup 1.0000x reference)
//
#include <hip/hip_runtime.h>
#include <hip/hip_fp16.h>

#define EPS 1e-15f
#define BKT_SHIFT 7
#define BKT_SIZE 128
#define NBKT_MAX 512

typedef _Float16 v8h __attribute__((ext_vector_type(8)));
typedef float v4f __attribute__((ext_vector_type(4)));

// ---------------------------------------------------------------------------
// Helpers
// ---------------------------------------------------------------------------
__device__ __forceinline__ int load_idx(const int* __restrict__ ei, int is64, int pos) {
    return is64 ? ei[(size_t)2 * pos] : ei[pos];
}

__device__ __forceinline__ int h2_as_int(__half2 h) {
    int w; __builtin_memcpy(&w, &h, 4); return w;
}
__device__ __forceinline__ __half2 int_as_h2(int w) {
    __half2 h; __builtin_memcpy(&h, &w, 4); return h;
}

// Detect whether edge_index arrived as int64 (odd int32 words all zero) or int32.
__global__ void detect_kernel(const int* __restrict__ ei, int* __restrict__ flag) {
    __shared__ int any_odd;
    if (threadIdx.x == 0) any_odd = 0;
    __syncthreads();
    if (ei[2 * threadIdx.x + 1] != 0) atomicOr(&any_odd, 1);
    __syncthreads();
    if (threadIdx.x == 0) *flag = any_odd ? 0 : 1;
}

// Bucket histogram: LDS-aggregated, 4096 edges/block.
__global__ __launch_bounds__(256) void bhist_kernel(
    const int* __restrict__ ei, const int* __restrict__ flag,
    int* __restrict__ bcnt, int E, int nbkt) {
    __shared__ int cnt[NBKT_MAX];
    int t = threadIdx.x;
    for (int u = t; u < nbkt; u += 256) cnt[u] = 0;
    __syncthreads();
    int is64 = *flag;
    int e0 = blockIdx.x * 4096;
#pragma unroll
    for (int i = 0; i < 16; ++i) {
        int e = e0 + i * 256 + t;
        if (e < E) atomicAdd(&cnt[load_idx(ei, is64, E + e) >> BKT_SHIFT], 1);
    }
    __syncthreads();
    for (int u = t; u < nbkt; u += 256)
        if (cnt[u]) atomicAdd(&bcnt[u], cnt[u]);
}

// Exclusive scan over bcnt[nbkt] (nbkt <= 512), one block of 512 threads.
__global__ void bscan_kernel(const int* __restrict__ bcnt, int* __restrict__ bbase,
                             int* __restrict__ bcursor, int nbkt, int E) {
    __shared__ int s[512];
    int t = threadIdx.x;
    int v = (t < nbkt) ? bcnt[t] : 0;
    s[t] = v;
    __syncthreads();
    for (int o = 1; o < 512; o <<= 1) {
        int u = (t >= o) ? s[t - o] : 0;
        __syncthreads();
        s[t] += u;
        __syncthreads();
    }
    if (t < nbkt) { int ex = s[t] - v; bbase[t] = ex; bcursor[t] = ex; }
    if (t == 0) bbase[nbkt] = E;
}

// ---------------------------------------------------------------------------
// Scatter: block-aggregated bucket reservation; computes all 6 gaussians;
// writes final rec = { src | dstloc<<25, h2(g1_0,g1_1), h2(g1_2,g2_0),
//                      h2(g2_1,g2_2) }  (16B), bucket-grouped, unordered.
// ---------------------------------------------------------------------------
__global__ __launch_bounds__(256) void scatter_rec(
    const int* __restrict__ ei, const int* __restrict__ flag,
    const float2* __restrict__ ea,
    const float* __restrict__ mu1, const float* __restrict__ sg1,
    const float* __restrict__ mu2, const float* __restrict__ sg2,
    int* __restrict__ bcursor, int4* __restrict__ rec, int E, int nbkt) {
    __shared__ int lcnt[NBKT_MAX];
    __shared__ int lbase[NBKT_MAX];
    int t = threadIdx.x;
    for (int u = t; u < nbkt; u += 256) lcnt[u] = 0;
    __syncthreads();
    int is64 = *flag;
    int e0 = blockIdx.x * 1024;

    int src[4], dst[4], rk[4];
    float2 a[4];
#pragma unroll
    for (int i = 0; i < 4; ++i) {
        int e = e0 + i * 256 + t;
        if (e < E) {
            src[i] = load_idx(ei, is64, e);
            dst[i] = load_idx(ei, is64, E + e);
            a[i] = ea[e];
            rk[i] = atomicAdd(&lcnt[dst[i] >> BKT_SHIFT], 1);
        } else dst[i] = -1;
    }
    __syncthreads();
    for (int u = t; u < nbkt; u += 256)
        if (lcnt[u] > 0) lbase[u] = atomicAdd(&bcursor[u], lcnt[u]);
    __syncthreads();

    float m1x[3], m1y[3], i1x[3], i1y[3], m2x[3], m2y[3], i2x[3], i2y[3];
#pragma unroll
    for (int k = 0; k < 3; ++k) {
        m1x[k] = mu1[2 * k]; m1y[k] = mu1[2 * k + 1];
        float s0 = sg1[2 * k], s1 = sg1[2 * k + 1];
        i1x[k] = -0.5f / (EPS + s0 * s0); i1y[k] = -0.5f / (EPS + s1 * s1);
        m2x[k] = mu2[2 * k]; m2y[k] = mu2[2 * k + 1];
        s0 = sg2[2 * k]; s1 = sg2[2 * k + 1];
        i2x[k] = -0.5f / (EPS + s0 * s0); i2y[k] = -0.5f / (EPS + s1 * s1);
    }

#pragma unroll
    for (int i = 0; i < 4; ++i) {
        if (dst[i] < 0) continue;
        float g1v[3], g2v[3];
#pragma unroll
        for (int k = 0; k < 3; ++k) {
            float d0 = a[i].x - m1x[k], d1 = a[i].y - m1y[k];
            g1v[k] = __expf(d0 * d0 * i1x[k] + d1 * d1 * i1y[k]);
            d0 = a[i].x - m2x[k]; d1 = a[i].y - m2y[k];
            g2v[k] = __expf(d0 * d0 * i2x[k] + d1 * d1 * i2y[k]);
        }
        int pos = lbase[dst[i] >> BKT_SHIFT] + rk[i];
        int4 r;
        r.x = src[i] | ((dst[i] & (BKT_SIZE - 1)) << 25);
        r.y = h2_as_int(__floats2half2_rn(g1v[0], g1v[1]));
        r.z = h2_as_int(__floats2half2_rn(g1v[2], g2v[0]));
        r.w = h2_as_int(__floats2half2_rn(g2v[1], g2v[2]));
        rec[pos] = r;
    }
}

// ---------------------------------------------------------------------------
// Bprep: fragment-ordered fp16 copy of W = [g1 | r1]  (128 x 256).
// ---------------------------------------------------------------------------
__global__ void bprep_kernel(const float* __restrict__ g1, const float* __restrict__ r1,
                             __half* __restrict__ Bprep) {
    int gid = blockIdx.x * 256 + threadIdx.x;   // 32768 total
    if (gid >= 32768) return;
    int fi = gid >> 9;
    int lane = (gid >> 3) & 63;
    int i = gid & 7;
    int ks = fi & 3, cb = fi >> 2;
    int k = ks * 32 + (lane >> 4) * 8 + i;
    int c = cb * 16 + (lane & 15);
    float v = (c < 192) ? g1[k * 192 + c] : r1[k * 64 + (c - 192)];
    Bprep[gid] = __float2half(v);
}

// ---------------------------------------------------------------------------
// Layer-1 GEMM via MFMA f16: x [M,128] fp32 -> hw1h [M,256] fp16.
// ---------------------------------------------------------------------------
__global__ __launch_bounds__(256) void gemm1_mfma(
    const float* __restrict__ A, const __half* __restrict__ Bprep,
    __half* __restrict__ Cout, int M) {
    __shared__ char a_lds[128 * 256];
    int row0 = blockIdx.x * 128;
    int tid = threadIdx.x;

    {
        int r = tid >> 1;
        int kh = (tid & 1) * 64;
        int gr = row0 + r;
        bool valid = gr < M;
        const float4* src = reinterpret_cast<const float4*>(A + (size_t)gr * 128 + kh);
#pragma unroll
        for (int i = 0; i < 8; ++i) {
            float4 f0 = valid ? src[2 * i]     : make_float4(0.f, 0.f, 0.f, 0.f);
            float4 f1 = valid ? src[2 * i + 1] : make_float4(0.f, 0.f, 0.f, 0.f);
            int4 v;
            v.x = h2_as_int(__floats2half2_rn(f0.x, f0.y));
            v.y = h2_as_int(__floats2half2_rn(f0.z, f0.w));
            v.z = h2_as_int(__floats2half2_rn(f1.x, f1.y));
            v.w = h2_as_int(__floats2half2_rn(f1.z, f1.w));
            int byte = r * 256 + kh * 2 + i * 16;
            byte ^= (r & 7) << 4;
            *reinterpret_cast<int4*>(&a_lds[byte]) = v;
        }
    }

    int wid = tid >> 6, lane = tid & 63;
    int wr = wid & 1, wc = wid >> 1;

    v8h bf[4][4];
#pragma unroll
    for (int cf = 0; cf < 4; ++cf)
#pragma unroll
        for (int ks = 0; ks < 4; ++ks) {
            int cb = blockIdx.y * 8 + wc * 4 + cf;
            int fi = cb * 4 + ks;
            bf[cf][ks] = *reinterpret_cast<const v8h*>(Bprep + (size_t)fi * 512 + lane * 8);
        }

    __syncthreads();

    v4f acc[4][4] = {};
#pragma unroll
    for (int ks = 0; ks < 4; ++ks) {
        v8h af[4];
#pragma unroll
        for (int rf = 0; rf < 4; ++rf) {
            int r = wr * 64 + rf * 16 + (lane & 15);
            int byte = r * 256 + ks * 64 + (lane >> 4) * 16;
            byte ^= (r & 7) << 4;
            af[rf] = *reinterpret_cast<const v8h*>(&a_lds[byte]);
        }
#pragma unroll
        for (int rf = 0; rf < 4; ++rf)
#pragma unroll
            for (int cf = 0; cf < 4; ++cf)
                acc[rf][cf] = __builtin_amdgcn_mfma_f32_16x16x32_f16(
                    af[rf], bf[cf][ks], acc[rf][cf], 0, 0, 0);
    }

#pragma unroll
    for (int rf = 0; rf < 4; ++rf)
#pragma unroll
        for (int cf = 0; cf < 4; ++cf)
#pragma unroll
            for (int i = 0; i < 4; ++i) {
                int gr = row0 + wr * 64 + rf * 16 + (lane >> 4) * 4 + i;
                int gc = blockIdx.y * 128 + wc * 64 + cf * 16 + (lane & 15);
                if (gr < M) Cout[(size_t)gr * 256 + gc] = __float2half(acc[rf][cf][i]);
            }
}

// ---------------------------------------------------------------------------
// Vector GEMM (layer 2): Cout[n,c] = A[n,:] @ [W1|W2], fp16 out.
// ---------------------------------------------------------------------------
template<int K, int TN, int TC, int C1, int C2>
__global__ __launch_bounds__(256) void gemm_cat(
    const float* __restrict__ A, const float* __restrict__ W1,
    const float* __restrict__ W2, __half* __restrict__ Cout, int nrows) {
    constexpr int NT = TN / 8;
    constexpr int CT = TC / 4;
    static_assert(NT * CT == 256, "bad tile");
    constexpr int COLS = C1 + C2;
    __shared__ float xs[TN][K + 4];

    int row0 = blockIdx.x * TN;
    int col0 = blockIdx.y * TC;

    constexpr int NV = TN * (K / 4);
    for (int id = threadIdx.x; id < NV; id += 256) {
        int r  = id / (K / 4);
        int k4 = id % (K / 4);
        int gr = row0 + r;
        float4 v = make_float4(0.f, 0.f, 0.f, 0.f);
        if (gr < nrows) v = reinterpret_cast<const float4*>(A + (size_t)gr * K)[k4];
        *reinterpret_cast<float4*>(&xs[r][4 * k4]) = v;
    }
    __syncthreads();

    int ct = threadIdx.x % CT;
    int nt = threadIdx.x / CT;
    int c0 = col0 + ct * 4;

    const float* wp;
    int wstride;
    if (c0 < C1) { wp = W1 + c0;        wstride = C1; }
    else         { wp = W2 + (c0 - C1); wstride = C2; }

    float acc[8][4] = {};
#pragma unroll 4
    for (int k = 0; k < K; ++k) {
        float4 w = *reinterpret_cast<const float4*>(wp + (size_t)k * wstride);
        float xr[8];
#pragma unroll
        for (int i = 0; i < 8; ++i) xr[i] = xs[nt * 8 + i][k];
#pragma unroll
        for (int i = 0; i < 8; ++i) {
            acc[i][0] += xr[i] * w.x;
            acc[i][1] += xr[i] * w.y;
            acc[i][2] += xr[i] * w.z;
            acc[i][3] += xr[i] * w.w;
        }
    }

#pragma unroll
    for (int i = 0; i < 8; ++i) {
        int gr = row0 + nt * 8 + i;
        if (gr < nrows) {
            __half2* p = reinterpret_cast<__half2*>(Cout + (size_t)gr * COLS + c0);
            p[0] = __floats2half2_rn(acc[i][0], acc[i][1]);
            p[1] = __floats2half2_rn(acc[i][2], acc[i][3]);
        }
    }
}

// ---------------------------------------------------------------------------
// agg1_bucket: one block (1024 thr, 16 waves) per 128-node bucket.
// LDS acc[128][64] fp32 + ds_add_f32; lane m gathers hw1h[src*256 + k*64 + m].
// Epilogue: mean + root + bias + ELU -> h2; writes deg.
// ---------------------------------------------------------------------------
__global__ __launch_bounds__(1024) void agg1_bucket(
    const int4* __restrict__ rec, const int* __restrict__ bbase,
    const __half* __restrict__ hw1h, const float* __restrict__ b1,
    float* __restrict__ h2, int* __restrict__ deg_g, int N) {
    __shared__ float acc[BKT_SIZE * 64];
    __shared__ int ldeg[BKT_SIZE];
    int t = threadIdx.x;
    int b = blockIdx.x;
    int node0 = b << BKT_SHIFT;
    for (int i = t; i < BKT_SIZE * 64; i += 1024) acc[i] = 0.f;
    if (t < BKT_SIZE) ldeg[t] = 0;
    __syncthreads();

    int beg = bbase[b], end = bbase[b + 1];
    int wid = t >> 6, lane = t & 63;

#define AGG1_EDGE(J) {                                                        \
        int4 r = rec[J];                                                      \
        int src = r.x & 0x1FFFFFF;                                            \
        int dl = ((unsigned)r.x) >> 25;                                       \
        __half2 ha = int_as_h2(r.y), hb = int_as_h2(r.z);                     \
        float g0 = __low2float(ha), g1 = __high2float(ha), g2 = __low2float(hb); \
        const __half* p = hw1h + (size_t)src * 256 + lane;                    \
        float v = g0 * __half2float(p[0]) + g1 * __half2float(p[64])          \
                + g2 * __half2float(p[128]);                                  \
        atomicAdd(&acc[(dl << 6) + lane], v);                                 \
        if (lane == 0) atomicAdd(&ldeg[dl], 1);                               \
    }

    int j = beg + wid;
    for (; j + 16 < end; j += 32) { AGG1_EDGE(j); AGG1_EDGE(j + 16); }
    if (j < end) AGG1_EDGE(j);
#undef AGG1_EDGE

    __syncthreads();
    int nn = min(BKT_SIZE, N - node0);
    for (int idx = t; idx < (nn << 6); idx += 1024) {
        int node = idx >> 6, m = idx & 63;
        int gn = node0 + node;
        float d = fmaxf((float)ldeg[node], 1.f);
        float v = acc[idx] / d + __half2float(hw1h[(size_t)gn * 256 + 192 + m]) + b1[m];
        h2[(size_t)gn * 64 + m] = v > 0.f ? v : expm1f(v);
    }
    if (t < nn) deg_g[node0 + t] = ldeg[t];
}

// ---------------------------------------------------------------------------
// agg2_bucket: one block (1024 thr) per bucket. LDS acc[128][16] fp32.
// 4 edges per wave-iteration (16 lanes each). Epilogue: log_softmax.
// ---------------------------------------------------------------------------
__global__ __launch_bounds__(1024) void agg2_bucket(
    const int4* __restrict__ rec, const int* __restrict__ bbase,
    const __half* __restrict__ hw2h, const float* __restrict__ b2,
    const int* __restrict__ deg_g, float* __restrict__ out, int N) {
    __shared__ float acc[BKT_SIZE * 16];
    int t = threadIdx.x;
    int b = blockIdx.x;
    int node0 = b << BKT_SHIFT;
    for (int i = t; i < BKT_SIZE * 16; i += 1024) acc[i] = 0.f;
    __syncthreads();

    int beg = bbase[b], end = bbase[b + 1];
    int wid = t >> 6, lane = t & 63;
    int eg = lane >> 4, c = lane & 15;

    for (int j0 = beg + wid * 4; j0 < end; j0 += 64) {
        int j = j0 + eg;
        if (j < end) {
            int4 r = rec[j];
            int src = r.x & 0x1FFFFFF;
            int dl = ((unsigned)r.x) >> 25;
            __half2 hb = int_as_h2(r.z), hc = int_as_h2(r.w);
            float g0 = __high2float(hb), g1 = __low2float(hc), g2 = __high2float(hc);
            const __half* p = hw2h + (size_t)src * 64 + c;
            float v = g0 * __half2float(p[0]) + g1 * __half2float(p[16])
                    + g2 * __half2float(p[32]);
            atomicAdd(&acc[(dl << 4) + c], v);
        }
    }
    __syncthreads();

    int nn = min(BKT_SIZE, N - node0);
    int node = t >> 3, l = t & 7;
    if (node < nn) {
        int gn = node0 + node;
        float d = fmaxf((float)deg_g[gn], 1.f);
        float a0 = acc[(node << 4) + 2 * l], a1 = acc[(node << 4) + 2 * l + 1];
        float r0 = __half2float(hw2h[(size_t)gn * 64 + 48 + 2 * l]);
        float r1 = __half2float(hw2h[(size_t)gn * 64 + 48 + 2 * l + 1]);
        float2 bb = reinterpret_cast<const float2*>(b2)[l];
        float v0 = a0 / d + r0 + bb.x;
        float v1 = a1 / d + r1 + bb.y;
        float mx = fmaxf(v0, v1);
#pragma unroll
        for (int off = 4; off >= 1; off >>= 1) mx = fmaxf(mx, __shfl_xor(mx, off, 8));
        float s = __expf(v0 - mx) + __expf(v1 - mx);
#pragma unroll
        for (int off = 4; off >= 1; off >>= 1) s += __shfl_xor(s, off, 8);
        float ls = __logf(s);
        reinterpret_cast<float2*>(out + (size_t)gn * 16)[l] = make_float2(v0 - mx - ls,
                                                                          v1 - mx - ls);
    }
}

// ---------------------------------------------------------------------------
extern "C" void kernel_launch(void* const* d_in, const int* in_sizes, int n_in,
                              void* d_out, int out_size, void* d_ws, size_t ws_size,
                              hipStream_t stream) {
    const float* x   = (const float*)d_in[0];
    const int*   ei  = (const int*)d_in[1];
    const float* ea  = (const float*)d_in[2];
    const float* g1  = (const float*)d_in[3];
    const float* mu1 = (const float*)d_in[4];
    const float* sg1 = (const float*)d_in[5];
    const float* r1  = (const float*)d_in[6];
    const float* b1  = (const float*)d_in[7];
    const float* g2  = (const float*)d_in[8];
    const float* mu2 = (const float*)d_in[9];
    const float* sg2 = (const float*)d_in[10];
    const float* r2  = (const float*)d_in[11];
    const float* b2  = (const float*)d_in[12];

    const int N = in_sizes[0] / 128;   // 50000
    const int E = in_sizes[2] / 2;     // 800000
    const int nbkt = (N + BKT_SIZE - 1) >> BKT_SHIFT;   // 391

    // Workspace layout
    __half* hw1h = (__half*)d_ws;                         // N*256 halves (25.6MB)
    float*  h2   = (float*)(hw1h + (size_t)N * 256);      // N*64 fp32
    __half* hw2h = (__half*)(h2 + (size_t)N * 64);        // N*64 halves
    int4*   rec  = (int4*)(hw2h + (size_t)N * 64);        // E int4 (12.8MB)
    __half* Bprep = (__half*)(rec + E);                   // 32768 halves
    int*    bcnt    = (int*)(Bprep + 32768);              // nbkt
    int*    bbase   = bcnt + nbkt;                        // nbkt+1
    int*    bcursor = bbase + nbkt + 1;                   // nbkt
    int*    deg_g   = bcursor + nbkt;                     // N
    int*    flag    = deg_g + N;                          // 1

    hipMemsetAsync(bcnt, 0, sizeof(int) * nbkt, stream);

    detect_kernel<<<1, 256, 0, stream>>>(ei, flag);
    bhist_kernel<<<(E + 4095) / 4096, 256, 0, stream>>>(ei, flag, bcnt, E, nbkt);
    bscan_kernel<<<1, 512, 0, stream>>>(bcnt, bbase, bcursor, nbkt, E);
    scatter_rec<<<(E + 1023) / 1024, 256, 0, stream>>>(
        ei, flag, (const float2*)ea, mu1, sg1, mu2, sg2, bcursor, rec, E, nbkt);

    // Layer 1 GEMM (MFMA): x [N,128] @ [g1|root1] -> hw1h fp16 [N,256]
    bprep_kernel<<<128, 256, 0, stream>>>(g1, r1, Bprep);
    gemm1_mfma<<<dim3((N + 127) / 128, 2), 256, 0, stream>>>(x, Bprep, hw1h, N);

    agg1_bucket<<<nbkt, 1024, 0, stream>>>(rec, bbase, hw1h, b1, h2, deg_g, N);

    // Layer 2 GEMM: h2 [N,64] @ [g2|root2] [64,64] -> hw2h (fp16)
    gemm_cat<64, 128, 64, 48, 16>
        <<<dim3((N + 127) / 128, 1), 256, 0, stream>>>(h2, g2, r2, hw2h, N);

    agg2_bucket<<<nbkt, 1024, 0, stream>>>(rec, bbase, hw2h, b2, deg_g,
                                           (float*)d_out, N);
}

// Round 7
// 200.681 us; speedup vs baseline: 2.7897x; 2.7897x over previous
//
#include <hip/hip_runtime.h>
#include <hip/hip_fp16.h>

#define EPS 1e-15f
#define BKT_SHIFT 7
#define BKT_SIZE 128
#define NBKT_MAX 512

typedef _Float16 v8h __attribute__((ext_vector_type(8)));
typedef float v4f __attribute__((ext_vector_type(4)));

// ---------------------------------------------------------------------------
// Helpers
// ---------------------------------------------------------------------------
__device__ __forceinline__ int load_idx(const int* __restrict__ ei, int is64, int pos) {
    return is64 ? ei[(size_t)2 * pos] : ei[pos];
}

__device__ __forceinline__ int h2_as_int(__half2 h) {
    int w; __builtin_memcpy(&w, &h, 4); return w;
}
__device__ __forceinline__ __half2 int_as_h2(int w) {
    __half2 h; __builtin_memcpy(&h, &w, 4); return h;
}

// Detect whether edge_index arrived as int64 (odd int32 words all zero) or int32.
__global__ void detect_kernel(const int* __restrict__ ei, int* __restrict__ flag) {
    __shared__ int any_odd;
    if (threadIdx.x == 0) any_odd = 0;
    __syncthreads();
    if (ei[2 * threadIdx.x + 1] != 0) atomicOr(&any_odd, 1);
    __syncthreads();
    if (threadIdx.x == 0) *flag = any_odd ? 0 : 1;
}

__global__ void hist_kernel(const int* __restrict__ ei, const int* __restrict__ flag,
                            int* __restrict__ deg, int E) {
    int e = blockIdx.x * 256 + threadIdx.x;
    if (e >= E) return;
    int dst = load_idx(ei, *flag, E + e);
    atomicAdd(&deg[dst], 1);
}

// ---- block-tiled exclusive scan over deg[N] ----
__global__ void scan_part(const int* __restrict__ deg, int* __restrict__ bsum, int N) {
    __shared__ int s[256];
    int i = blockIdx.x * 256 + threadIdx.x;
    s[threadIdx.x] = (i < N) ? deg[i] : 0;
    __syncthreads();
    for (int o = 128; o > 0; o >>= 1) {
        if (threadIdx.x < o) s[threadIdx.x] += s[threadIdx.x + o];
        __syncthreads();
    }
    if (threadIdx.x == 0) bsum[blockIdx.x] = s[0];
}

__global__ void scan_base(int* __restrict__ bsum, int NB, int* __restrict__ rowptrN, int E) {
    __shared__ int s[256];
    int v = (threadIdx.x < NB) ? bsum[threadIdx.x] : 0;
    s[threadIdx.x] = v;
    __syncthreads();
    for (int o = 1; o < 256; o <<= 1) {
        int t = (threadIdx.x >= o) ? s[threadIdx.x - o] : 0;
        __syncthreads();
        s[threadIdx.x] += t;
        __syncthreads();
    }
    if (threadIdx.x < NB) bsum[threadIdx.x] = s[threadIdx.x] - v;  // exclusive
    if (threadIdx.x == 0) *rowptrN = E;
}

__global__ void scan_final(const int* __restrict__ deg, const int* __restrict__ bsum,
                           int* __restrict__ rowptr, int N) {
    __shared__ int s[256];
    int i = blockIdx.x * 256 + threadIdx.x;
    int v = (i < N) ? deg[i] : 0;
    s[threadIdx.x] = v;
    __syncthreads();
    for (int o = 1; o < 256; o <<= 1) {
        int t = (threadIdx.x >= o) ? s[threadIdx.x - o] : 0;
        __syncthreads();
        s[threadIdx.x] += t;
        __syncthreads();
    }
    int excl = s[threadIdx.x] - v + bsum[blockIdx.x];
    if (i < N) rowptr[i] = excl;
}

// bcursor[b] = rowptr[b * BKT_SIZE]
__global__ void bkt_init(const int* __restrict__ rowptr, int* __restrict__ bcursor,
                         int nbkt) {
    int b = blockIdx.x * 256 + threadIdx.x;
    if (b < nbkt) bcursor[b] = rowptr[b << BKT_SHIFT];
}

// ---------------------------------------------------------------------------
// Pass 1: bucket multisplit, 8192 edges per 1024-thread block, two-phase
// (count -> reserve -> place via LDS running cursors). Long (~21-record)
// contiguous runs per bucket make the 16B stores L2-assembled dense lines.
// Packet {src, dst, ax, ay}.
// ---------------------------------------------------------------------------
__global__ __launch_bounds__(1024) void pass1_kernel(
    const int* __restrict__ ei, const int* __restrict__ flag,
    const float2* __restrict__ ea, int* __restrict__ bcursor,
    int4* __restrict__ staging, int E, int nbkt) {
    __shared__ int lcnt[NBKT_MAX];
    __shared__ int lcur[NBKT_MAX];
    int t = threadIdx.x;
    if (t < nbkt) lcnt[t] = 0;
    __syncthreads();
    int is64 = *flag;
    int e0 = blockIdx.x * 8192;
    int eend = min(e0 + 8192, E);

    // Phase A: count bucket occupancy for this block's edge range
    for (int e = e0 + t; e < eend; e += 1024)
        atomicAdd(&lcnt[load_idx(ei, is64, E + e) >> BKT_SHIFT], 1);
    __syncthreads();

    // Reserve contiguous runs in each bucket's global region
    if (t < nbkt) {
        int c = lcnt[t];
        lcur[t] = c ? atomicAdd(&bcursor[t], c) : 0;
    }
    __syncthreads();

    // Phase B: place packets via LDS running cursors
    for (int e = e0 + t; e < eend; e += 1024) {
        int src = load_idx(ei, is64, e);
        int dst = load_idx(ei, is64, E + e);
        float2 a = ea[e];
        int pos = atomicAdd(&lcur[dst >> BKT_SHIFT], 1);
        staging[pos] = make_int4(src, dst,
                                 __float_as_int(a.x), __float_as_int(a.y));
    }
}

// ---------------------------------------------------------------------------
// Pass 2: one block per bucket. Final dst-order placement via LDS cursors,
// gaussians computed here. Random stores confined to a ~32KB region (L2-hot).
//   rec = {src:int32, h2(g1_0,g1_1), h2(g1_2,g2_0), h2(g2_1,g2_2)}
// ---------------------------------------------------------------------------
__global__ __launch_bounds__(256) void pass2_kernel(
    const int4* __restrict__ staging, const int* __restrict__ rowptr,
    const float* __restrict__ mu1, const float* __restrict__ sg1,
    const float* __restrict__ mu2, const float* __restrict__ sg2,
    int4* __restrict__ rec, int N) {
    __shared__ int lcur[BKT_SIZE];
    int b = blockIdx.x;
    int node0 = b << BKT_SHIFT;
    int t = threadIdx.x;
    int nn = min(BKT_SIZE, N - node0);
    if (t < nn) lcur[t] = rowptr[node0 + t];
    __syncthreads();
    int beg = rowptr[node0];
    int end = rowptr[min(node0 + BKT_SIZE, N)];

    float m1x[3], m1y[3], i1x[3], i1y[3], m2x[3], m2y[3], i2x[3], i2y[3];
#pragma unroll
    for (int k = 0; k < 3; ++k) {
        m1x[k] = mu1[2 * k]; m1y[k] = mu1[2 * k + 1];
        float s0 = sg1[2 * k], s1 = sg1[2 * k + 1];
        i1x[k] = -0.5f / (EPS + s0 * s0); i1y[k] = -0.5f / (EPS + s1 * s1);
        m2x[k] = mu2[2 * k]; m2y[k] = mu2[2 * k + 1];
        s0 = sg2[2 * k]; s1 = sg2[2 * k + 1];
        i2x[k] = -0.5f / (EPS + s0 * s0); i2y[k] = -0.5f / (EPS + s1 * s1);
    }

    for (int j = beg + t; j < end; j += 256) {
        int4 p = staging[j];
        float ax = __int_as_float(p.z), ay = __int_as_float(p.w);
        float g1v[3], g2v[3];
#pragma unroll
        for (int k = 0; k < 3; ++k) {
            float d0 = ax - m1x[k], d1 = ay - m1y[k];
            g1v[k] = __expf(d0 * d0 * i1x[k] + d1 * d1 * i1y[k]);
            d0 = ax - m2x[k]; d1 = ay - m2y[k];
            g2v[k] = __expf(d0 * d0 * i2x[k] + d1 * d1 * i2y[k]);
        }
        int pos = atomicAdd(&lcur[p.y & (BKT_SIZE - 1)], 1);
        int4 r;
        r.x = p.x;
        r.y = h2_as_int(__floats2half2_rn(g1v[0], g1v[1]));
        r.z = h2_as_int(__floats2half2_rn(g1v[2], g2v[0]));
        r.w = h2_as_int(__floats2half2_rn(g2v[1], g2v[2]));
        rec[pos] = r;
    }
}

// ---------------------------------------------------------------------------
// Bprep: fragment-ordered fp16 copy of W = [g1 | r1]  (128 x 256).
// ---------------------------------------------------------------------------
__global__ void bprep_kernel(const float* __restrict__ g1, const float* __restrict__ r1,
                             __half* __restrict__ Bprep) {
    int gid = blockIdx.x * 256 + threadIdx.x;   // 32768 total
    if (gid >= 32768) return;
    int fi = gid >> 9;
    int lane = (gid >> 3) & 63;
    int i = gid & 7;
    int ks = fi & 3, cb = fi >> 2;
    int k = ks * 32 + (lane >> 4) * 8 + i;
    int c = cb * 16 + (lane & 15);
    float v = (c < 192) ? g1[k * 192 + c] : r1[k * 64 + (c - 192)];
    Bprep[gid] = __float2half(v);
}

// ---------------------------------------------------------------------------
// Layer-1 GEMM via MFMA f16: x [M,128] fp32 -> hw1h [M,256] fp16.
// ---------------------------------------------------------------------------
__global__ __launch_bounds__(256) void gemm1_mfma(
    const float* __restrict__ A, const __half* __restrict__ Bprep,
    __half* __restrict__ Cout, int M) {
    __shared__ char a_lds[128 * 256];
    int row0 = blockIdx.x * 128;
    int tid = threadIdx.x;

    {
        int r = tid >> 1;
        int kh = (tid & 1) * 64;
        int gr = row0 + r;
        bool valid = gr < M;
        const float4* src = reinterpret_cast<const float4*>(A + (size_t)gr * 128 + kh);
#pragma unroll
        for (int i = 0; i < 8; ++i) {
            float4 f0 = valid ? src[2 * i]     : make_float4(0.f, 0.f, 0.f, 0.f);
            float4 f1 = valid ? src[2 * i + 1] : make_float4(0.f, 0.f, 0.f, 0.f);
            int4 v;
            v.x = h2_as_int(__floats2half2_rn(f0.x, f0.y));
            v.y = h2_as_int(__floats2half2_rn(f0.z, f0.w));
            v.z = h2_as_int(__floats2half2_rn(f1.x, f1.y));
            v.w = h2_as_int(__floats2half2_rn(f1.z, f1.w));
            int byte = r * 256 + kh * 2 + i * 16;
            byte ^= (r & 7) << 4;
            *reinterpret_cast<int4*>(&a_lds[byte]) = v;
        }
    }

    int wid = tid >> 6, lane = tid & 63;
    int wr = wid & 1, wc = wid >> 1;

    v8h bf[4][4];
#pragma unroll
    for (int cf = 0; cf < 4; ++cf)
#pragma unroll
        for (int ks = 0; ks < 4; ++ks) {
            int cb = blockIdx.y * 8 + wc * 4 + cf;
            int fi = cb * 4 + ks;
            bf[cf][ks] = *reinterpret_cast<const v8h*>(Bprep + (size_t)fi * 512 + lane * 8);
        }

    __syncthreads();

    v4f acc[4][4] = {};
#pragma unroll
    for (int ks = 0; ks < 4; ++ks) {
        v8h af[4];
#pragma unroll
        for (int rf = 0; rf < 4; ++rf) {
            int r = wr * 64 + rf * 16 + (lane & 15);
            int byte = r * 256 + ks * 64 + (lane >> 4) * 16;
            byte ^= (r & 7) << 4;
            af[rf] = *reinterpret_cast<const v8h*>(&a_lds[byte]);
        }
#pragma unroll
        for (int rf = 0; rf < 4; ++rf)
#pragma unroll
            for (int cf = 0; cf < 4; ++cf)
                acc[rf][cf] = __builtin_amdgcn_mfma_f32_16x16x32_f16(
                    af[rf], bf[cf][ks], acc[rf][cf], 0, 0, 0);
    }

#pragma unroll
    for (int rf = 0; rf < 4; ++rf)
#pragma unroll
        for (int cf = 0; cf < 4; ++cf)
#pragma unroll
            for (int i = 0; i < 4; ++i) {
                int gr = row0 + wr * 64 + rf * 16 + (lane >> 4) * 4 + i;
                int gc = blockIdx.y * 128 + wc * 64 + cf * 16 + (lane & 15);
                if (gr < M) Cout[(size_t)gr * 256 + gc] = __float2half(acc[rf][cf][i]);
            }
}

// ---------------------------------------------------------------------------
// Vector GEMM (layer 2): Cout[n,c] = A[n,:] @ [W1|W2], fp16 out.
// ---------------------------------------------------------------------------
template<int K, int TN, int TC, int C1, int C2>
__global__ __launch_bounds__(256) void gemm_cat(
    const float* __restrict__ A, const float* __restrict__ W1,
    const float* __restrict__ W2, __half* __restrict__ Cout, int nrows) {
    constexpr int NT = TN / 8;
    constexpr int CT = TC / 4;
    static_assert(NT * CT == 256, "bad tile");
    constexpr int COLS = C1 + C2;
    __shared__ float xs[TN][K + 4];

    int row0 = blockIdx.x * TN;
    int col0 = blockIdx.y * TC;

    constexpr int NV = TN * (K / 4);
    for (int id = threadIdx.x; id < NV; id += 256) {
        int r  = id / (K / 4);
        int k4 = id % (K / 4);
        int gr = row0 + r;
        float4 v = make_float4(0.f, 0.f, 0.f, 0.f);
        if (gr < nrows) v = reinterpret_cast<const float4*>(A + (size_t)gr * K)[k4];
        *reinterpret_cast<float4*>(&xs[r][4 * k4]) = v;
    }
    __syncthreads();

    int ct = threadIdx.x % CT;
    int nt = threadIdx.x / CT;
    int c0 = col0 + ct * 4;

    const float* wp;
    int wstride;
    if (c0 < C1) { wp = W1 + c0;        wstride = C1; }
    else         { wp = W2 + (c0 - C1); wstride = C2; }

    float acc[8][4] = {};
#pragma unroll 4
    for (int k = 0; k < K; ++k) {
        float4 w = *reinterpret_cast<const float4*>(wp + (size_t)k * wstride);
        float xr[8];
#pragma unroll
        for (int i = 0; i < 8; ++i) xr[i] = xs[nt * 8 + i][k];
#pragma unroll
        for (int i = 0; i < 8; ++i) {
            acc[i][0] += xr[i] * w.x;
            acc[i][1] += xr[i] * w.y;
            acc[i][2] += xr[i] * w.z;
            acc[i][3] += xr[i] * w.w;
        }
    }

#pragma unroll
    for (int i = 0; i < 8; ++i) {
        int gr = row0 + nt * 8 + i;
        if (gr < nrows) {
            __half2* p = reinterpret_cast<__half2*>(Cout + (size_t)gr * COLS + c0);
            p[0] = __floats2half2_rn(acc[i][0], acc[i][1]);
            p[1] = __floats2half2_rn(acc[i][2], acc[i][3]);
        }
    }
}

// ---------------------------------------------------------------------------
// agg1: 32 lanes per node, lane owns m = {2l, 2l+1} via half2.
// ---------------------------------------------------------------------------
__global__ __launch_bounds__(256) void agg1_kernel(
    const int4* __restrict__ rec, const int* __restrict__ rowptr,
    const __half* __restrict__ hw1h, const float* __restrict__ b1,
    float* __restrict__ h2, int N) {
    int node = (blockIdx.x * 256 + threadIdx.x) >> 5;
    int l = threadIdx.x & 31;
    if (node >= N) return;
    int beg = rowptr[node], end = rowptr[node + 1];
    float ax0 = 0.f, ay0 = 0.f, ax1 = 0.f, ay1 = 0.f;
    int j = beg;
    for (; j + 1 < end; j += 2) {
        int4 r0 = rec[j], r1 = rec[j + 1];
        __half2 ha0 = int_as_h2(r0.y), hb0 = int_as_h2(r0.z);
        __half2 ha1 = int_as_h2(r1.y), hb1 = int_as_h2(r1.z);
        float g00 = __low2float(ha0), g01 = __high2float(ha0), g02 = __low2float(hb0);
        float g10 = __low2float(ha1), g11 = __high2float(ha1), g12 = __low2float(hb1);
        const __half2* p0 = reinterpret_cast<const __half2*>(hw1h + (size_t)(r0.x & 0x1FFFFFF) * 256);
        const __half2* p1 = reinterpret_cast<const __half2*>(hw1h + (size_t)(r1.x & 0x1FFFFFF) * 256);
        float2 f00 = __half22float2(p0[l]);
        float2 f01 = __half22float2(p0[32 + l]);
        float2 f02 = __half22float2(p0[64 + l]);
        float2 f10 = __half22float2(p1[l]);
        float2 f11 = __half22float2(p1[32 + l]);
        float2 f12 = __half22float2(p1[64 + l]);
        ax0 += g00 * f00.x + g01 * f01.x + g02 * f02.x;
        ay0 += g00 * f00.y + g01 * f01.y + g02 * f02.y;
        ax1 += g10 * f10.x + g11 * f11.x + g12 * f12.x;
        ay1 += g10 * f10.y + g11 * f11.y + g12 * f12.y;
    }
    if (j < end) {
        int4 r0 = rec[j];
        __half2 ha0 = int_as_h2(r0.y), hb0 = int_as_h2(r0.z);
        float g00 = __low2float(ha0), g01 = __high2float(ha0), g02 = __low2float(hb0);
        const __half2* p0 = reinterpret_cast<const __half2*>(hw1h + (size_t)(r0.x & 0x1FFFFFF) * 256);
        float2 f00 = __half22float2(p0[l]);
        float2 f01 = __half22float2(p0[32 + l]);
        float2 f02 = __half22float2(p0[64 + l]);
        ax0 += g00 * f00.x + g01 * f01.x + g02 * f02.x;
        ay0 += g00 * f00.y + g01 * f01.y + g02 * f02.y;
    }
    float d = fmaxf((float)(end - beg), 1.0f);
    float2 root = __half22float2(
        reinterpret_cast<const __half2*>(hw1h + (size_t)node * 256 + 192)[l]);
    float2 bb = reinterpret_cast<const float2*>(b1)[l];
    float v0 = (ax0 + ax1) / d + root.x + bb.x;
    float v1 = (ay0 + ay1) / d + root.y + bb.y;
    float2 o;
    o.x = v0 > 0.f ? v0 : expm1f(v0);
    o.y = v1 > 0.f ? v1 : expm1f(v1);
    reinterpret_cast<float2*>(h2 + (size_t)node * 64)[l] = o;
}

// ---------------------------------------------------------------------------
// agg2: 8 lanes per node, lane owns c = {2l, 2l+1} via half2.
// ---------------------------------------------------------------------------
__global__ __launch_bounds__(256) void agg2_kernel(
    const int4* __restrict__ rec, const int* __restrict__ rowptr,
    const __half* __restrict__ hw2h, const float* __restrict__ b2,
    float* __restrict__ out, int N) {
    int node = (blockIdx.x * 256 + threadIdx.x) >> 3;
    int l = threadIdx.x & 7;
    if (node >= N) return;
    int beg = rowptr[node], end = rowptr[node + 1];
    float ax = 0.f, ay = 0.f;
    for (int j = beg; j < end; ++j) {
        int4 r = rec[j];
        __half2 hb = int_as_h2(r.z), hc = int_as_h2(r.w);
        float g0 = __high2float(hb), g1 = __low2float(hc), g2 = __high2float(hc);
        const __half2* p = reinterpret_cast<const __half2*>(hw2h + (size_t)(r.x & 0x1FFFFFF) * 64);
        float2 f0 = __half22float2(p[l]);
        float2 f1 = __half22float2(p[8 + l]);
        float2 f2 = __half22float2(p[16 + l]);
        ax += g0 * f0.x + g1 * f1.x + g2 * f2.x;
        ay += g0 * f0.y + g1 * f1.y + g2 * f2.y;
    }
    float d = fmaxf((float)(end - beg), 1.0f);
    float2 root = __half22float2(
        reinterpret_cast<const __half2*>(hw2h + (size_t)node * 64 + 48)[l]);
    float2 bb = reinterpret_cast<const float2*>(b2)[l];
    float v0 = ax / d + root.x + bb.x;
    float v1 = ay / d + root.y + bb.y;

    float mx = fmaxf(v0, v1);
#pragma unroll
    for (int off = 4; off >= 1; off >>= 1) mx = fmaxf(mx, __shfl_xor(mx, off, 8));
    float s = __expf(v0 - mx) + __expf(v1 - mx);
#pragma unroll
    for (int off = 4; off >= 1; off >>= 1) s += __shfl_xor(s, off, 8);
    float ls = __logf(s);
    float2 o = make_float2(v0 - mx - ls, v1 - mx - ls);
    reinterpret_cast<float2*>(out + (size_t)node * 16)[l] = o;
}

// ---------------------------------------------------------------------------
extern "C" void kernel_launch(void* const* d_in, const int* in_sizes, int n_in,
                              void* d_out, int out_size, void* d_ws, size_t ws_size,
                              hipStream_t stream) {
    const float* x   = (const float*)d_in[0];
    const int*   ei  = (const int*)d_in[1];
    const float* ea  = (const float*)d_in[2];
    const float* g1  = (const float*)d_in[3];
    const float* mu1 = (const float*)d_in[4];
    const float* sg1 = (const float*)d_in[5];
    const float* r1  = (const float*)d_in[6];
    const float* b1  = (const float*)d_in[7];
    const float* g2  = (const float*)d_in[8];
    const float* mu2 = (const float*)d_in[9];
    const float* sg2 = (const float*)d_in[10];
    const float* r2  = (const float*)d_in[11];
    const float* b2  = (const float*)d_in[12];

    const int N = in_sizes[0] / 128;   // 50000
    const int E = in_sizes[2] / 2;     // 800000
    const int NB = (N + 255) / 256;
    const int nbkt = (N + BKT_SIZE - 1) >> BKT_SHIFT;   // 391

    // Workspace layout
    __half* hw1h = (__half*)d_ws;                         // N*256 halves (25.6MB)
    float*  h2   = (float*)(hw1h + (size_t)N * 256);      // N*64 fp32
    __half* hw2h = (__half*)(h2 + (size_t)N * 64);        // N*64 halves
    int4*   rec  = (int4*)(hw2h + (size_t)N * 64);        // E int4 (12.8MB)
    int4*   staging = rec + E;                            // E int4 (12.8MB)
    __half* Bprep = (__half*)(staging + E);               // 32768 halves
    int*    deg    = (int*)(Bprep + 32768);               // N
    int*    rowptr = deg + N;                             // N+1
    int*    bcursor = rowptr + N + 1;                     // nbkt
    int*    bsum   = bcursor + nbkt;                      // 256
    int*    flag   = bsum + 256;                          // 1

    hipMemsetAsync(deg, 0, sizeof(int) * N, stream);

    detect_kernel<<<1, 256, 0, stream>>>(ei, flag);
    hist_kernel<<<(E + 255) / 256, 256, 0, stream>>>(ei, flag, deg, E);
    scan_part<<<NB, 256, 0, stream>>>(deg, bsum, N);
    scan_base<<<1, 256, 0, stream>>>(bsum, NB, rowptr + N, E);
    scan_final<<<NB, 256, 0, stream>>>(deg, bsum, rowptr, N);
    bkt_init<<<(nbkt + 255) / 256, 256, 0, stream>>>(rowptr, bcursor, nbkt);

    pass1_kernel<<<(E + 8191) / 8192, 1024, 0, stream>>>(
        ei, flag, (const float2*)ea, bcursor, staging, E, nbkt);
    pass2_kernel<<<nbkt, 256, 0, stream>>>(
        staging, rowptr, mu1, sg1, mu2, sg2, rec, N);

    // Layer 1 GEMM (MFMA): x [N,128] @ [g1|root1] -> hw1h fp16 [N,256]
    bprep_kernel<<<128, 256, 0, stream>>>(g1, r1, Bprep);
    gemm1_mfma<<<dim3((N + 127) / 128, 2), 256, 0, stream>>>(x, Bprep, hw1h, N);

    agg1_kernel<<<((size_t)N * 32 + 255) / 256, 256, 0, stream>>>(
        rec, rowptr, hw1h, b1, h2, N);

    // Layer 2 GEMM: h2 [N,64] @ [g2|root2] [64,64] -> hw2h (fp16)
    gemm_cat<64, 128, 64, 48, 16>
        <<<dim3((N + 127) / 128, 1), 256, 0, stream>>>(h2, g2, r2, hw2h, N);

    agg2_kernel<<<((size_t)N * 8 + 255) / 256, 256, 0, stream>>>(
        rec, rowptr, hw2h, b2, (float*)d_out, N);
}

// Round 8
// 167.195 us; speedup vs baseline: 3.3484x; 1.2003x over previous
//
#include <hip/hip_runtime.h>
#include <hip/hip_fp16.h>

#define EPS 1e-15f
#define BKT_SHIFT 7
#define BKT_SIZE 128
#define NBKT_MAX 512

typedef _Float16 v8h __attribute__((ext_vector_type(8)));
typedef float v4f __attribute__((ext_vector_type(4)));

// ---------------------------------------------------------------------------
// Helpers
// ---------------------------------------------------------------------------
__device__ __forceinline__ int load_idx(const int* __restrict__ ei, int is64, int pos) {
    return is64 ? ei[(size_t)2 * pos] : ei[pos];
}

__device__ __forceinline__ int h2_as_int(__half2 h) {
    int w; __builtin_memcpy(&w, &h, 4); return w;
}
__device__ __forceinline__ __half2 int_as_h2(int w) {
    __half2 h; __builtin_memcpy(&h, &w, 4); return h;
}

// Detect whether edge_index arrived as int64 (odd int32 words all zero) or int32.
__global__ void detect_kernel(const int* __restrict__ ei, int* __restrict__ flag) {
    __shared__ int any_odd;
    if (threadIdx.x == 0) any_odd = 0;
    __syncthreads();
    if (ei[2 * threadIdx.x + 1] != 0) atomicOr(&any_odd, 1);
    __syncthreads();
    if (threadIdx.x == 0) *flag = any_odd ? 0 : 1;
}

// Bucket histogram: LDS-aggregated, 4096 edges/block.
__global__ __launch_bounds__(256) void bhist_kernel(
    const int* __restrict__ ei, const int* __restrict__ flag,
    int* __restrict__ bcnt, int E, int nbkt) {
    __shared__ int cnt[NBKT_MAX];
    int t = threadIdx.x;
    for (int u = t; u < nbkt; u += 256) cnt[u] = 0;
    __syncthreads();
    int is64 = *flag;
    int e0 = blockIdx.x * 4096;
#pragma unroll
    for (int i = 0; i < 16; ++i) {
        int e = e0 + i * 256 + t;
        if (e < E) atomicAdd(&cnt[load_idx(ei, is64, E + e) >> BKT_SHIFT], 1);
    }
    __syncthreads();
    for (int u = t; u < nbkt; u += 256)
        if (cnt[u]) atomicAdd(&bcnt[u], cnt[u]);
}

// Exclusive scan over bcnt[nbkt] (nbkt <= 512); also bbase[nbkt]=E, rowptr[N]=E.
__global__ void bscan_kernel(const int* __restrict__ bcnt, int* __restrict__ bbase,
                             int* __restrict__ bcursor, int* __restrict__ rowptrN,
                             int nbkt, int E) {
    __shared__ int s[512];
    int t = threadIdx.x;
    int v = (t < nbkt) ? bcnt[t] : 0;
    s[t] = v;
    __syncthreads();
    for (int o = 1; o < 512; o <<= 1) {
        int u = (t >= o) ? s[t - o] : 0;
        __syncthreads();
        s[t] += u;
        __syncthreads();
    }
    if (t < nbkt) { int ex = s[t] - v; bbase[t] = ex; bcursor[t] = ex; }
    if (t == 0) { bbase[nbkt] = E; *rowptrN = E; }
}

// ---------------------------------------------------------------------------
// Pass 1: bucket multisplit, 8192 edges per 1024-thread block, two-phase
// (count -> reserve -> place via LDS running cursors). Packet {src,dst,ax,ay}.
// ---------------------------------------------------------------------------
__global__ __launch_bounds__(1024) void pass1_kernel(
    const int* __restrict__ ei, const int* __restrict__ flag,
    const float2* __restrict__ ea, int* __restrict__ bcursor,
    int4* __restrict__ staging, int E, int nbkt) {
    __shared__ int lcnt[NBKT_MAX];
    __shared__ int lcur[NBKT_MAX];
    int t = threadIdx.x;
    if (t < nbkt) lcnt[t] = 0;
    __syncthreads();
    int is64 = *flag;
    int e0 = blockIdx.x * 8192;
    int eend = min(e0 + 8192, E);

    for (int e = e0 + t; e < eend; e += 1024)
        atomicAdd(&lcnt[load_idx(ei, is64, E + e) >> BKT_SHIFT], 1);
    __syncthreads();

    if (t < nbkt) {
        int c = lcnt[t];
        lcur[t] = c ? atomicAdd(&bcursor[t], c) : 0;
    }
    __syncthreads();

    for (int e = e0 + t; e < eend; e += 1024) {
        int src = load_idx(ei, is64, e);
        int dst = load_idx(ei, is64, E + e);
        float2 a = ea[e];
        int pos = atomicAdd(&lcur[dst >> BKT_SHIFT], 1);
        staging[pos] = make_int4(src, dst,
                                 __float_as_int(a.x), __float_as_int(a.y));
    }
}

// ---------------------------------------------------------------------------
// Pass 2: one block per bucket. Derives per-node rowptr internally (count ->
// LDS scan -> write rowptr), then places records dst-ordered with gaussians.
//   rec = {src:int32, h2(g1_0,g1_1), h2(g1_2,g2_0), h2(g2_1,g2_2)}
// ---------------------------------------------------------------------------
__global__ __launch_bounds__(256) void pass2_kernel(
    const int4* __restrict__ staging, const int* __restrict__ bbase,
    const float* __restrict__ mu1, const float* __restrict__ sg1,
    const float* __restrict__ mu2, const float* __restrict__ sg2,
    int4* __restrict__ rec, int* __restrict__ rowptr, int N) {
    __shared__ int lcnt[BKT_SIZE];
    __shared__ int ssc[BKT_SIZE];
    __shared__ int lcur[BKT_SIZE];
    int b = blockIdx.x;
    int node0 = b << BKT_SHIFT;
    int t = threadIdx.x;
    int beg = bbase[b], end = bbase[b + 1];

    if (t < BKT_SIZE) lcnt[t] = 0;
    __syncthreads();
    // Phase A: per-node degree within this bucket
    for (int j = beg + t; j < end; j += 256)
        atomicAdd(&lcnt[staging[j].y & (BKT_SIZE - 1)], 1);
    __syncthreads();
    // 128-entry exclusive LDS scan (uniform control flow for syncthreads)
    int v = (t < BKT_SIZE) ? lcnt[t] : 0;
    if (t < BKT_SIZE) ssc[t] = v;
    __syncthreads();
    for (int o = 1; o < BKT_SIZE; o <<= 1) {
        int u = (t < BKT_SIZE && t >= o) ? ssc[t - o] : 0;
        __syncthreads();
        if (t < BKT_SIZE) ssc[t] += u;
        __syncthreads();
    }
    if (t < BKT_SIZE) {
        int excl = beg + ssc[t] - v;
        lcur[t] = excl;
        if (node0 + t < N) rowptr[node0 + t] = excl;
    }
    __syncthreads();

    float m1x[3], m1y[3], i1x[3], i1y[3], m2x[3], m2y[3], i2x[3], i2y[3];
#pragma unroll
    for (int k = 0; k < 3; ++k) {
        m1x[k] = mu1[2 * k]; m1y[k] = mu1[2 * k + 1];
        float s0 = sg1[2 * k], s1 = sg1[2 * k + 1];
        i1x[k] = -0.5f / (EPS + s0 * s0); i1y[k] = -0.5f / (EPS + s1 * s1);
        m2x[k] = mu2[2 * k]; m2y[k] = mu2[2 * k + 1];
        s0 = sg2[2 * k]; s1 = sg2[2 * k + 1];
        i2x[k] = -0.5f / (EPS + s0 * s0); i2y[k] = -0.5f / (EPS + s1 * s1);
    }

    // Phase B: place records
    for (int j = beg + t; j < end; j += 256) {
        int4 p = staging[j];
        float ax = __int_as_float(p.z), ay = __int_as_float(p.w);
        float g1v[3], g2v[3];
#pragma unroll
        for (int k = 0; k < 3; ++k) {
            float d0 = ax - m1x[k], d1 = ay - m1y[k];
            g1v[k] = __expf(d0 * d0 * i1x[k] + d1 * d1 * i1y[k]);
            d0 = ax - m2x[k]; d1 = ay - m2y[k];
            g2v[k] = __expf(d0 * d0 * i2x[k] + d1 * d1 * i2y[k]);
        }
        int pos = atomicAdd(&lcur[p.y & (BKT_SIZE - 1)], 1);
        int4 r;
        r.x = p.x;
        r.y = h2_as_int(__floats2half2_rn(g1v[0], g1v[1]));
        r.z = h2_as_int(__floats2half2_rn(g1v[2], g2v[0]));
        r.w = h2_as_int(__floats2half2_rn(g2v[1], g2v[2]));
        rec[pos] = r;
    }
}

// ---------------------------------------------------------------------------
// Bprep: fragment-ordered fp16 copy of W = [g1 | r1]  (128 x 256).
// ---------------------------------------------------------------------------
__global__ void bprep_kernel(const float* __restrict__ g1, const float* __restrict__ r1,
                             __half* __restrict__ Bprep) {
    int gid = blockIdx.x * 256 + threadIdx.x;   // 32768 total
    if (gid >= 32768) return;
    int fi = gid >> 9;
    int lane = (gid >> 3) & 63;
    int i = gid & 7;
    int ks = fi & 3, cb = fi >> 2;
    int k = ks * 32 + (lane >> 4) * 8 + i;
    int c = cb * 16 + (lane & 15);
    float v = (c < 192) ? g1[k * 192 + c] : r1[k * 64 + (c - 192)];
    Bprep[gid] = __float2half(v);
}

// ---------------------------------------------------------------------------
// Layer-1 GEMM via MFMA f16: x [M,128] fp32 -> hw1h [M,256] fp16.
// ---------------------------------------------------------------------------
__global__ __launch_bounds__(256) void gemm1_mfma(
    const float* __restrict__ A, const __half* __restrict__ Bprep,
    __half* __restrict__ Cout, int M) {
    __shared__ char a_lds[128 * 256];
    int row0 = blockIdx.x * 128;
    int tid = threadIdx.x;

    {
        int r = tid >> 1;
        int kh = (tid & 1) * 64;
        int gr = row0 + r;
        bool valid = gr < M;
        const float4* src = reinterpret_cast<const float4*>(A + (size_t)gr * 128 + kh);
#pragma unroll
        for (int i = 0; i < 8; ++i) {
            float4 f0 = valid ? src[2 * i]     : make_float4(0.f, 0.f, 0.f, 0.f);
            float4 f1 = valid ? src[2 * i + 1] : make_float4(0.f, 0.f, 0.f, 0.f);
            int4 v;
            v.x = h2_as_int(__floats2half2_rn(f0.x, f0.y));
            v.y = h2_as_int(__floats2half2_rn(f0.z, f0.w));
            v.z = h2_as_int(__floats2half2_rn(f1.x, f1.y));
            v.w = h2_as_int(__floats2half2_rn(f1.z, f1.w));
            int byte = r * 256 + kh * 2 + i * 16;
            byte ^= (r & 7) << 4;
            *reinterpret_cast<int4*>(&a_lds[byte]) = v;
        }
    }

    int wid = tid >> 6, lane = tid & 63;
    int wr = wid & 1, wc = wid >> 1;

    v8h bf[4][4];
#pragma unroll
    for (int cf = 0; cf < 4; ++cf)
#pragma unroll
        for (int ks = 0; ks < 4; ++ks) {
            int cb = blockIdx.y * 8 + wc * 4 + cf;
            int fi = cb * 4 + ks;
            bf[cf][ks] = *reinterpret_cast<const v8h*>(Bprep + (size_t)fi * 512 + lane * 8);
        }

    __syncthreads();

    v4f acc[4][4] = {};
#pragma unroll
    for (int ks = 0; ks < 4; ++ks) {
        v8h af[4];
#pragma unroll
        for (int rf = 0; rf < 4; ++rf) {
            int r = wr * 64 + rf * 16 + (lane & 15);
            int byte = r * 256 + ks * 64 + (lane >> 4) * 16;
            byte ^= (r & 7) << 4;
            af[rf] = *reinterpret_cast<const v8h*>(&a_lds[byte]);
        }
#pragma unroll
        for (int rf = 0; rf < 4; ++rf)
#pragma unroll
            for (int cf = 0; cf < 4; ++cf)
                acc[rf][cf] = __builtin_amdgcn_mfma_f32_16x16x32_f16(
                    af[rf], bf[cf][ks], acc[rf][cf], 0, 0, 0);
    }

#pragma unroll
    for (int rf = 0; rf < 4; ++rf)
#pragma unroll
        for (int cf = 0; cf < 4; ++cf)
#pragma unroll
            for (int i = 0; i < 4; ++i) {
                int gr = row0 + wr * 64 + rf * 16 + (lane >> 4) * 4 + i;
                int gc = blockIdx.y * 128 + wc * 64 + cf * 16 + (lane & 15);
                if (gr < M) Cout[(size_t)gr * 256 + gc] = __float2half(acc[rf][cf][i]);
            }
}

// ---------------------------------------------------------------------------
// Vector GEMM (layer 2): Cout[n,c] = A[n,:] @ [W1|W2], fp16 out.
// ---------------------------------------------------------------------------
template<int K, int TN, int TC, int C1, int C2>
__global__ __launch_bounds__(256) void gemm_cat(
    const float* __restrict__ A, const float* __restrict__ W1,
    const float* __restrict__ W2, __half* __restrict__ Cout, int nrows) {
    constexpr int NT = TN / 8;
    constexpr int CT = TC / 4;
    static_assert(NT * CT == 256, "bad tile");
    constexpr int COLS = C1 + C2;
    __shared__ float xs[TN][K + 4];

    int row0 = blockIdx.x * TN;
    int col0 = blockIdx.y * TC;

    constexpr int NV = TN * (K / 4);
    for (int id = threadIdx.x; id < NV; id += 256) {
        int r  = id / (K / 4);
        int k4 = id % (K / 4);
        int gr = row0 + r;
        float4 v = make_float4(0.f, 0.f, 0.f, 0.f);
        if (gr < nrows) v = reinterpret_cast<const float4*>(A + (size_t)gr * K)[k4];
        *reinterpret_cast<float4*>(&xs[r][4 * k4]) = v;
    }
    __syncthreads();

    int ct = threadIdx.x % CT;
    int nt = threadIdx.x / CT;
    int c0 = col0 + ct * 4;

    const float* wp;
    int wstride;
    if (c0 < C1) { wp = W1 + c0;        wstride = C1; }
    else         { wp = W2 + (c0 - C1); wstride = C2; }

    float acc[8][4] = {};
#pragma unroll 4
    for (int k = 0; k < K; ++k) {
        float4 w = *reinterpret_cast<const float4*>(wp + (size_t)k * wstride);
        float xr[8];
#pragma unroll
        for (int i = 0; i < 8; ++i) xr[i] = xs[nt * 8 + i][k];
#pragma unroll
        for (int i = 0; i < 8; ++i) {
            acc[i][0] += xr[i] * w.x;
            acc[i][1] += xr[i] * w.y;
            acc[i][2] += xr[i] * w.z;
            acc[i][3] += xr[i] * w.w;
        }
    }

#pragma unroll
    for (int i = 0; i < 8; ++i) {
        int gr = row0 + nt * 8 + i;
        if (gr < nrows) {
            __half2* p = reinterpret_cast<__half2*>(Cout + (size_t)gr * COLS + c0);
            p[0] = __floats2half2_rn(acc[i][0], acc[i][1]);
            p[1] = __floats2half2_rn(acc[i][2], acc[i][3]);
        }
    }
}

// ---------------------------------------------------------------------------
// agg1: 32 lanes per node, lane owns m = {2l, 2l+1} via half2; unroll 4.
// ---------------------------------------------------------------------------
__global__ __launch_bounds__(256) void agg1_kernel(
    const int4* __restrict__ rec, const int* __restrict__ rowptr,
    const __half* __restrict__ hw1h, const float* __restrict__ b1,
    float* __restrict__ h2, int N) {
    int node = (blockIdx.x * 256 + threadIdx.x) >> 5;
    int l = threadIdx.x & 31;
    if (node >= N) return;
    int beg = rowptr[node], end = rowptr[node + 1];
    float ax0 = 0.f, ay0 = 0.f, ax1 = 0.f, ay1 = 0.f;
    int j = beg;
    for (; j + 3 < end; j += 4) {
        int4 r0 = rec[j], r1 = rec[j + 1], r2 = rec[j + 2], r3 = rec[j + 3];
        const __half2* p0 = reinterpret_cast<const __half2*>(hw1h + (size_t)r0.x * 256);
        const __half2* p1 = reinterpret_cast<const __half2*>(hw1h + (size_t)r1.x * 256);
        const __half2* p2 = reinterpret_cast<const __half2*>(hw1h + (size_t)r2.x * 256);
        const __half2* p3 = reinterpret_cast<const __half2*>(hw1h + (size_t)r3.x * 256);
        __half2 f00 = p0[l], f01 = p0[32 + l], f02 = p0[64 + l];
        __half2 f10 = p1[l], f11 = p1[32 + l], f12 = p1[64 + l];
        __half2 f20 = p2[l], f21 = p2[32 + l], f22 = p2[64 + l];
        __half2 f30 = p3[l], f31 = p3[32 + l], f32 = p3[64 + l];
        __half2 ha0 = int_as_h2(r0.y), hb0 = int_as_h2(r0.z);
        __half2 ha1 = int_as_h2(r1.y), hb1 = int_as_h2(r1.z);
        __half2 ha2 = int_as_h2(r2.y), hb2 = int_as_h2(r2.z);
        __half2 ha3 = int_as_h2(r3.y), hb3 = int_as_h2(r3.z);
        {
            float g0 = __low2float(ha0), g1 = __high2float(ha0), g2 = __low2float(hb0);
            float2 a = __half22float2(f00), b = __half22float2(f01), c = __half22float2(f02);
            ax0 += g0 * a.x + g1 * b.x + g2 * c.x;
            ay0 += g0 * a.y + g1 * b.y + g2 * c.y;
        }
        {
            float g0 = __low2float(ha1), g1 = __high2float(ha1), g2 = __low2float(hb1);
            float2 a = __half22float2(f10), b = __half22float2(f11), c = __half22float2(f12);
            ax1 += g0 * a.x + g1 * b.x + g2 * c.x;
            ay1 += g0 * a.y + g1 * b.y + g2 * c.y;
        }
        {
            float g0 = __low2float(ha2), g1 = __high2float(ha2), g2 = __low2float(hb2);
            float2 a = __half22float2(f20), b = __half22float2(f21), c = __half22float2(f22);
            ax0 += g0 * a.x + g1 * b.x + g2 * c.x;
            ay0 += g0 * a.y + g1 * b.y + g2 * c.y;
        }
        {
            float g0 = __low2float(ha3), g1 = __high2float(ha3), g2 = __low2float(hb3);
            float2 a = __half22float2(f30), b = __half22float2(f31), c = __half22float2(f32);
            ax1 += g0 * a.x + g1 * b.x + g2 * c.x;
            ay1 += g0 * a.y + g1 * b.y + g2 * c.y;
        }
    }
    for (; j < end; ++j) {
        int4 r0 = rec[j];
        __half2 ha0 = int_as_h2(r0.y), hb0 = int_as_h2(r0.z);
        float g0 = __low2float(ha0), g1 = __high2float(ha0), g2 = __low2float(hb0);
        const __half2* p0 = reinterpret_cast<const __half2*>(hw1h + (size_t)r0.x * 256);
        float2 a = __half22float2(p0[l]);
        float2 b = __half22float2(p0[32 + l]);
        float2 c = __half22float2(p0[64 + l]);
        ax0 += g0 * a.x + g1 * b.x + g2 * c.x;
        ay0 += g0 * a.y + g1 * b.y + g2 * c.y;
    }
    float d = fmaxf((float)(end - beg), 1.0f);
    float2 root = __half22float2(
        reinterpret_cast<const __half2*>(hw1h + (size_t)node * 256 + 192)[l]);
    float2 bb = reinterpret_cast<const float2*>(b1)[l];
    float v0 = (ax0 + ax1) / d + root.x + bb.x;
    float v1 = (ay0 + ay1) / d + root.y + bb.y;
    float2 o;
    o.x = v0 > 0.f ? v0 : expm1f(v0);
    o.y = v1 > 0.f ? v1 : expm1f(v1);
    reinterpret_cast<float2*>(h2 + (size_t)node * 64)[l] = o;
}

// ---------------------------------------------------------------------------
// agg2: 8 lanes per node, lane owns c = {2l, 2l+1} via half2.
// ---------------------------------------------------------------------------
__global__ __launch_bounds__(256) void agg2_kernel(
    const int4* __restrict__ rec, const int* __restrict__ rowptr,
    const __half* __restrict__ hw2h, const float* __restrict__ b2,
    float* __restrict__ out, int N) {
    int node = (blockIdx.x * 256 + threadIdx.x) >> 3;
    int l = threadIdx.x & 7;
    if (node >= N) return;
    int beg = rowptr[node], end = rowptr[node + 1];
    float ax = 0.f, ay = 0.f;
    for (int j = beg; j < end; ++j) {
        int4 r = rec[j];
        __half2 hb = int_as_h2(r.z), hc = int_as_h2(r.w);
        float g0 = __high2float(hb), g1 = __low2float(hc), g2 = __high2float(hc);
        const __half2* p = reinterpret_cast<const __half2*>(hw2h + (size_t)r.x * 64);
        float2 f0 = __half22float2(p[l]);
        float2 f1 = __half22float2(p[8 + l]);
        float2 f2 = __half22float2(p[16 + l]);
        ax += g0 * f0.x + g1 * f1.x + g2 * f2.x;
        ay += g0 * f0.y + g1 * f1.y + g2 * f2.y;
    }
    float d = fmaxf((float)(end - beg), 1.0f);
    float2 root = __half22float2(
        reinterpret_cast<const __half2*>(hw2h + (size_t)node * 64 + 48)[l]);
    float2 bb = reinterpret_cast<const float2*>(b2)[l];
    float v0 = ax / d + root.x + bb.x;
    float v1 = ay / d + root.y + bb.y;

    float mx = fmaxf(v0, v1);
#pragma unroll
    for (int off = 4; off >= 1; off >>= 1) mx = fmaxf(mx, __shfl_xor(mx, off, 8));
    float s = __expf(v0 - mx) + __expf(v1 - mx);
#pragma unroll
    for (int off = 4; off >= 1; off >>= 1) s += __shfl_xor(s, off, 8);
    float ls = __logf(s);
    float2 o = make_float2(v0 - mx - ls, v1 - mx - ls);
    reinterpret_cast<float2*>(out + (size_t)node * 16)[l] = o;
}

// ---------------------------------------------------------------------------
extern "C" void kernel_launch(void* const* d_in, const int* in_sizes, int n_in,
                              void* d_out, int out_size, void* d_ws, size_t ws_size,
                              hipStream_t stream) {
    const float* x   = (const float*)d_in[0];
    const int*   ei  = (const int*)d_in[1];
    const float* ea  = (const float*)d_in[2];
    const float* g1  = (const float*)d_in[3];
    const float* mu1 = (const float*)d_in[4];
    const float* sg1 = (const float*)d_in[5];
    const float* r1  = (const float*)d_in[6];
    const float* b1  = (const float*)d_in[7];
    const float* g2  = (const float*)d_in[8];
    const float* mu2 = (const float*)d_in[9];
    const float* sg2 = (const float*)d_in[10];
    const float* r2  = (const float*)d_in[11];
    const float* b2  = (const float*)d_in[12];

    const int N = in_sizes[0] / 128;   // 50000
    const int E = in_sizes[2] / 2;     // 800000
    const int nbkt = (N + BKT_SIZE - 1) >> BKT_SHIFT;   // 391

    // Workspace layout
    __half* hw1h = (__half*)d_ws;                         // N*256 halves (25.6MB)
    float*  h2   = (float*)(hw1h + (size_t)N * 256);      // N*64 fp32
    __half* hw2h = (__half*)(h2 + (size_t)N * 64);        // N*64 halves
    int4*   rec  = (int4*)(hw2h + (size_t)N * 64);        // E int4 (12.8MB)
    int4*   staging = rec + E;                            // E int4 (12.8MB)
    __half* Bprep = (__half*)(staging + E);               // 32768 halves
    int*    rowptr  = (int*)(Bprep + 32768);              // N+1
    int*    bcnt    = rowptr + N + 1;                     // nbkt
    int*    bbase   = bcnt + nbkt;                        // nbkt+1
    int*    bcursor = bbase + nbkt + 1;                   // nbkt
    int*    flag    = bcursor + nbkt;                     // 1

    hipMemsetAsync(bcnt, 0, sizeof(int) * nbkt, stream);

    detect_kernel<<<1, 256, 0, stream>>>(ei, flag);
    bhist_kernel<<<(E + 4095) / 4096, 256, 0, stream>>>(ei, flag, bcnt, E, nbkt);
    bscan_kernel<<<1, 512, 0, stream>>>(bcnt, bbase, bcursor, rowptr + N, nbkt, E);

    pass1_kernel<<<(E + 8191) / 8192, 1024, 0, stream>>>(
        ei, flag, (const float2*)ea, bcursor, staging, E, nbkt);
    pass2_kernel<<<nbkt, 256, 0, stream>>>(
        staging, bbase, mu1, sg1, mu2, sg2, rec, rowptr, N);

    // Layer 1 GEMM (MFMA): x [N,128] @ [g1|root1] -> hw1h fp16 [N,256]
    bprep_kernel<<<128, 256, 0, stream>>>(g1, r1, Bprep);
    gemm1_mfma<<<dim3((N + 127) / 128, 2), 256, 0, stream>>>(x, Bprep, hw1h, N);

    agg1_kernel<<<((size_t)N * 32 + 255) / 256, 256, 0, stream>>>(
        rec, rowptr, hw1h, b1, h2, N);

    // Layer 2 GEMM: h2 [N,64] @ [g2|root2] [64,64] -> hw2h (fp16)
    gemm_cat<64, 128, 64, 48, 16>
        <<<dim3((N + 127) / 128, 1), 256, 0, stream>>>(h2, g2, r2, hw2h, N);

    agg2_kernel<<<((size_t)N * 8 + 255) / 256, 256, 0, stream>>>(
        rec, rowptr, hw2h, b2, (float*)d_out, N);
}

// Round 9
// 151.808 us; speedup vs baseline: 3.6878x; 1.1014x over previous
//
#include <hip/hip_runtime.h>
#include <hip/hip_fp16.h>

#define EPS 1e-15f
#define BKT_SHIFT 7
#define BKT_SIZE 128
#define NBKT_MAX 512

typedef _Float16 v8h __attribute__((ext_vector_type(8)));
typedef float v4f __attribute__((ext_vector_type(4)));

// ---------------------------------------------------------------------------
// Helpers
// ---------------------------------------------------------------------------
__device__ __forceinline__ int load_idx(const int* __restrict__ ei, int is64, int pos) {
    return is64 ? ei[(size_t)2 * pos] : ei[pos];
}

__device__ __forceinline__ int h2_as_int(__half2 h) {
    int w; __builtin_memcpy(&w, &h, 4); return w;
}
__device__ __forceinline__ __half2 int_as_h2(int w) {
    __half2 h; __builtin_memcpy(&h, &w, 4); return h;
}

// Detect whether edge_index arrived as int64 (odd int32 words all zero) or int32.
__global__ void detect_kernel(const int* __restrict__ ei, int* __restrict__ flag) {
    __shared__ int any_odd;
    if (threadIdx.x == 0) any_odd = 0;
    __syncthreads();
    if (ei[2 * threadIdx.x + 1] != 0) atomicOr(&any_odd, 1);
    __syncthreads();
    if (threadIdx.x == 0) *flag = any_odd ? 0 : 1;
}

// Bucket histogram: LDS-aggregated, 4096 edges/block.
__global__ __launch_bounds__(256) void bhist_kernel(
    const int* __restrict__ ei, const int* __restrict__ flag,
    int* __restrict__ bcnt, int E, int nbkt) {
    __shared__ int cnt[NBKT_MAX];
    int t = threadIdx.x;
    for (int u = t; u < nbkt; u += 256) cnt[u] = 0;
    __syncthreads();
    int is64 = *flag;
    int e0 = blockIdx.x * 4096;
#pragma unroll
    for (int i = 0; i < 16; ++i) {
        int e = e0 + i * 256 + t;
        if (e < E) atomicAdd(&cnt[load_idx(ei, is64, E + e) >> BKT_SHIFT], 1);
    }
    __syncthreads();
    for (int u = t; u < nbkt; u += 256)
        if (cnt[u]) atomicAdd(&bcnt[u], cnt[u]);
}

// Exclusive scan over bcnt[nbkt] (nbkt <= 512); also bbase[nbkt]=E, rowptr[N]=E.
__global__ void bscan_kernel(const int* __restrict__ bcnt, int* __restrict__ bbase,
                             int* __restrict__ bcursor, int* __restrict__ rowptrN,
                             int nbkt, int E) {
    __shared__ int s[512];
    int t = threadIdx.x;
    int v = (t < nbkt) ? bcnt[t] : 0;
    s[t] = v;
    __syncthreads();
    for (int o = 1; o < 512; o <<= 1) {
        int u = (t >= o) ? s[t - o] : 0;
        __syncthreads();
        s[t] += u;
        __syncthreads();
    }
    if (t < nbkt) { int ex = s[t] - v; bbase[t] = ex; bcursor[t] = ex; }
    if (t == 0) { bbase[nbkt] = E; *rowptrN = E; }
}

// ---------------------------------------------------------------------------
// Pass 1: bucket multisplit, 8192 edges per 1024-thread block, two-phase
// (count -> reserve -> place via LDS running cursors). Packet {src,dst,ax,ay}.
// ---------------------------------------------------------------------------
__global__ __launch_bounds__(1024) void pass1_kernel(
    const int* __restrict__ ei, const int* __restrict__ flag,
    const float2* __restrict__ ea, int* __restrict__ bcursor,
    int4* __restrict__ staging, int E, int nbkt) {
    __shared__ int lcnt[NBKT_MAX];
    __shared__ int lcur[NBKT_MAX];
    int t = threadIdx.x;
    if (t < nbkt) lcnt[t] = 0;
    __syncthreads();
    int is64 = *flag;
    int e0 = blockIdx.x * 8192;
    int eend = min(e0 + 8192, E);

    for (int e = e0 + t; e < eend; e += 1024)
        atomicAdd(&lcnt[load_idx(ei, is64, E + e) >> BKT_SHIFT], 1);
    __syncthreads();

    if (t < nbkt) {
        int c = lcnt[t];
        lcur[t] = c ? atomicAdd(&bcursor[t], c) : 0;
    }
    __syncthreads();

    for (int e = e0 + t; e < eend; e += 1024) {
        int src = load_idx(ei, is64, e);
        int dst = load_idx(ei, is64, E + e);
        float2 a = ea[e];
        int pos = atomicAdd(&lcur[dst >> BKT_SHIFT], 1);
        staging[pos] = make_int4(src, dst,
                                 __float_as_int(a.x), __float_as_int(a.y));
    }
}

// ---------------------------------------------------------------------------
// Pass 2: one block per bucket. Derives per-node rowptr internally (count ->
// LDS scan -> write rowptr), then places records dst-ordered with gaussians.
//   rec = {src:int32, h2(g1_0,g1_1), h2(g1_2,g2_0), h2(g2_1,g2_2)}
// ---------------------------------------------------------------------------
__global__ __launch_bounds__(256) void pass2_kernel(
    const int4* __restrict__ staging, const int* __restrict__ bbase,
    const float* __restrict__ mu1, const float* __restrict__ sg1,
    const float* __restrict__ mu2, const float* __restrict__ sg2,
    int4* __restrict__ rec, int* __restrict__ rowptr, int N) {
    __shared__ int lcnt[BKT_SIZE];
    __shared__ int ssc[BKT_SIZE];
    __shared__ int lcur[BKT_SIZE];
    int b = blockIdx.x;
    int node0 = b << BKT_SHIFT;
    int t = threadIdx.x;
    int beg = bbase[b], end = bbase[b + 1];

    if (t < BKT_SIZE) lcnt[t] = 0;
    __syncthreads();
    for (int j = beg + t; j < end; j += 256)
        atomicAdd(&lcnt[staging[j].y & (BKT_SIZE - 1)], 1);
    __syncthreads();
    int v = (t < BKT_SIZE) ? lcnt[t] : 0;
    if (t < BKT_SIZE) ssc[t] = v;
    __syncthreads();
    for (int o = 1; o < BKT_SIZE; o <<= 1) {
        int u = (t < BKT_SIZE && t >= o) ? ssc[t - o] : 0;
        __syncthreads();
        if (t < BKT_SIZE) ssc[t] += u;
        __syncthreads();
    }
    if (t < BKT_SIZE) {
        int excl = beg + ssc[t] - v;
        lcur[t] = excl;
        if (node0 + t < N) rowptr[node0 + t] = excl;
    }
    __syncthreads();

    float m1x[3], m1y[3], i1x[3], i1y[3], m2x[3], m2y[3], i2x[3], i2y[3];
#pragma unroll
    for (int k = 0; k < 3; ++k) {
        m1x[k] = mu1[2 * k]; m1y[k] = mu1[2 * k + 1];
        float s0 = sg1[2 * k], s1 = sg1[2 * k + 1];
        i1x[k] = -0.5f / (EPS + s0 * s0); i1y[k] = -0.5f / (EPS + s1 * s1);
        m2x[k] = mu2[2 * k]; m2y[k] = mu2[2 * k + 1];
        s0 = sg2[2 * k]; s1 = sg2[2 * k + 1];
        i2x[k] = -0.5f / (EPS + s0 * s0); i2y[k] = -0.5f / (EPS + s1 * s1);
    }

    for (int j = beg + t; j < end; j += 256) {
        int4 p = staging[j];
        float ax = __int_as_float(p.z), ay = __int_as_float(p.w);
        float g1v[3], g2v[3];
#pragma unroll
        for (int k = 0; k < 3; ++k) {
            float d0 = ax - m1x[k], d1 = ay - m1y[k];
            g1v[k] = __expf(d0 * d0 * i1x[k] + d1 * d1 * i1y[k]);
            d0 = ax - m2x[k]; d1 = ay - m2y[k];
            g2v[k] = __expf(d0 * d0 * i2x[k] + d1 * d1 * i2y[k]);
        }
        int pos = atomicAdd(&lcur[p.y & (BKT_SIZE - 1)], 1);
        int4 r;
        r.x = p.x;
        r.y = h2_as_int(__floats2half2_rn(g1v[0], g1v[1]));
        r.z = h2_as_int(__floats2half2_rn(g1v[2], g2v[0]));
        r.w = h2_as_int(__floats2half2_rn(g2v[1], g2v[2]));
        rec[pos] = r;
    }
}

// ---------------------------------------------------------------------------
// Bprep: fragment-ordered fp16 copy of W = [g1 | r1]  (128 x 256).
// ---------------------------------------------------------------------------
__global__ void bprep_kernel(const float* __restrict__ g1, const float* __restrict__ r1,
                             __half* __restrict__ Bprep) {
    int gid = blockIdx.x * 256 + threadIdx.x;   // 32768 total
    if (gid >= 32768) return;
    int fi = gid >> 9;
    int lane = (gid >> 3) & 63;
    int i = gid & 7;
    int ks = fi & 3, cb = fi >> 2;
    int k = ks * 32 + (lane >> 4) * 8 + i;
    int c = cb * 16 + (lane & 15);
    float v = (c < 192) ? g1[k * 192 + c] : r1[k * 64 + (c - 192)];
    Bprep[gid] = __float2half(v);
}

// ---------------------------------------------------------------------------
// Layer-1 GEMM via MFMA f16: x [M,128] fp32 -> hw1h [M,256] fp16.
// BM=64, BN=128: grid (ceil(M/64), 2). 4 waves; wave wid computes 64 rows x
// 32 cols (4 rf x 2 cf frags). Coalesced A staging into swizzled 16KB LDS.
// ---------------------------------------------------------------------------
__global__ __launch_bounds__(256) void gemm1_mfma(
    const float* __restrict__ A, const __half* __restrict__ Bprep,
    __half* __restrict__ Cout, int M) {
    __shared__ char a_lds[64 * 256];   // 64 rows x 128 fp16, XOR-swizzled
    int row0 = blockIdx.x * 64;
    int tid = threadIdx.x;
    int wid = tid >> 6, lane = tid & 63;

    // Coalesced staging: thread handles float4 index j*256+tid (lane-contiguous)
    const float4* xf4 = reinterpret_cast<const float4*>(A);
#pragma unroll
    for (int j = 0; j < 8; ++j) {
        int g = j * 256 + tid;          // 0..2047 float4s (64 rows x 32/row)
        int r = g >> 5, c = g & 31;
        int gr = row0 + r;
        float4 f = (gr < M) ? xf4[(size_t)gr * 32 + c]
                            : make_float4(0.f, 0.f, 0.f, 0.f);
        int2 v;
        v.x = h2_as_int(__floats2half2_rn(f.x, f.y));
        v.y = h2_as_int(__floats2half2_rn(f.z, f.w));
        int byte = r * 256 + c * 8;
        byte ^= (r & 7) << 4;           // T2 swizzle
        *reinterpret_cast<int2*>(&a_lds[byte]) = v;
    }

    // Preload 8 loop-invariant B fragments (L2-resident)
    v8h bf[2][4];   // [cf][ks]
#pragma unroll
    for (int cf = 0; cf < 2; ++cf)
#pragma unroll
        for (int ks = 0; ks < 4; ++ks) {
            int cb = blockIdx.y * 8 + wid * 2 + cf;
            int fi = cb * 4 + ks;
            bf[cf][ks] = *reinterpret_cast<const v8h*>(Bprep + (size_t)fi * 512 + lane * 8);
        }

    __syncthreads();

    v4f acc[4][2] = {};   // [rf][cf]
#pragma unroll
    for (int ks = 0; ks < 4; ++ks) {
        v8h af[4];
#pragma unroll
        for (int rf = 0; rf < 4; ++rf) {
            int r = rf * 16 + (lane & 15);
            int byte = r * 256 + ks * 64 + (lane >> 4) * 16;
            byte ^= (r & 7) << 4;
            af[rf] = *reinterpret_cast<const v8h*>(&a_lds[byte]);
        }
#pragma unroll
        for (int rf = 0; rf < 4; ++rf)
#pragma unroll
            for (int cf = 0; cf < 2; ++cf)
                acc[rf][cf] = __builtin_amdgcn_mfma_f32_16x16x32_f16(
                    af[rf], bf[cf][ks], acc[rf][cf], 0, 0, 0);
    }

#pragma unroll
    for (int rf = 0; rf < 4; ++rf)
#pragma unroll
        for (int cf = 0; cf < 2; ++cf)
#pragma unroll
            for (int i = 0; i < 4; ++i) {
                int gr = row0 + rf * 16 + (lane >> 4) * 4 + i;
                int gc = blockIdx.y * 128 + wid * 32 + cf * 16 + (lane & 15);
                if (gr < M) Cout[(size_t)gr * 256 + gc] = __float2half(acc[rf][cf][i]);
            }
}

// ---------------------------------------------------------------------------
// Vector GEMM (layer 2): Cout[n,c] = A[n,:] @ [W1|W2], fp16 out.
// ---------------------------------------------------------------------------
template<int K, int TN, int TC, int C1, int C2>
__global__ __launch_bounds__(256) void gemm_cat(
    const float* __restrict__ A, const float* __restrict__ W1,
    const float* __restrict__ W2, __half* __restrict__ Cout, int nrows) {
    constexpr int NT = TN / 8;
    constexpr int CT = TC / 4;
    static_assert(NT * CT == 256, "bad tile");
    constexpr int COLS = C1 + C2;
    __shared__ float xs[TN][K + 4];

    int row0 = blockIdx.x * TN;
    int col0 = blockIdx.y * TC;

    constexpr int NV = TN * (K / 4);
    for (int id = threadIdx.x; id < NV; id += 256) {
        int r  = id / (K / 4);
        int k4 = id % (K / 4);
        int gr = row0 + r;
        float4 v = make_float4(0.f, 0.f, 0.f, 0.f);
        if (gr < nrows) v = reinterpret_cast<const float4*>(A + (size_t)gr * K)[k4];
        *reinterpret_cast<float4*>(&xs[r][4 * k4]) = v;
    }
    __syncthreads();

    int ct = threadIdx.x % CT;
    int nt = threadIdx.x / CT;
    int c0 = col0 + ct * 4;

    const float* wp;
    int wstride;
    if (c0 < C1) { wp = W1 + c0;        wstride = C1; }
    else         { wp = W2 + (c0 - C1); wstride = C2; }

    float acc[8][4] = {};
#pragma unroll 4
    for (int k = 0; k < K; ++k) {
        float4 w = *reinterpret_cast<const float4*>(wp + (size_t)k * wstride);
        float xr[8];
#pragma unroll
        for (int i = 0; i < 8; ++i) xr[i] = xs[nt * 8 + i][k];
#pragma unroll
        for (int i = 0; i < 8; ++i) {
            acc[i][0] += xr[i] * w.x;
            acc[i][1] += xr[i] * w.y;
            acc[i][2] += xr[i] * w.z;
            acc[i][3] += xr[i] * w.w;
        }
    }

#pragma unroll
    for (int i = 0; i < 8; ++i) {
        int gr = row0 + nt * 8 + i;
        if (gr < nrows) {
            __half2* p = reinterpret_cast<__half2*>(Cout + (size_t)gr * COLS + c0);
            p[0] = __floats2half2_rn(acc[i][0], acc[i][1]);
            p[1] = __floats2half2_rn(acc[i][2], acc[i][3]);
        }
    }
}

// ---------------------------------------------------------------------------
// agg1: 32 lanes per node, lane owns m = {2l, 2l+1} via half2; unroll 4.
// ---------------------------------------------------------------------------
__global__ __launch_bounds__(256) void agg1_kernel(
    const int4* __restrict__ rec, const int* __restrict__ rowptr,
    const __half* __restrict__ hw1h, const float* __restrict__ b1,
    float* __restrict__ h2, int N) {
    int node = (blockIdx.x * 256 + threadIdx.x) >> 5;
    int l = threadIdx.x & 31;
    if (node >= N) return;
    int beg = rowptr[node], end = rowptr[node + 1];
    float ax0 = 0.f, ay0 = 0.f, ax1 = 0.f, ay1 = 0.f;
    int j = beg;
    for (; j + 3 < end; j += 4) {
        int4 r0 = rec[j], r1 = rec[j + 1], r2 = rec[j + 2], r3 = rec[j + 3];
        const __half2* p0 = reinterpret_cast<const __half2*>(hw1h + (size_t)r0.x * 256);
        const __half2* p1 = reinterpret_cast<const __half2*>(hw1h + (size_t)r1.x * 256);
        const __half2* p2 = reinterpret_cast<const __half2*>(hw1h + (size_t)r2.x * 256);
        const __half2* p3 = reinterpret_cast<const __half2*>(hw1h + (size_t)r3.x * 256);
        __half2 f00 = p0[l], f01 = p0[32 + l], f02 = p0[64 + l];
        __half2 f10 = p1[l], f11 = p1[32 + l], f12 = p1[64 + l];
        __half2 f20 = p2[l], f21 = p2[32 + l], f22 = p2[64 + l];
        __half2 f30 = p3[l], f31 = p3[32 + l], f32 = p3[64 + l];
        __half2 ha0 = int_as_h2(r0.y), hb0 = int_as_h2(r0.z);
        __half2 ha1 = int_as_h2(r1.y), hb1 = int_as_h2(r1.z);
        __half2 ha2 = int_as_h2(r2.y), hb2 = int_as_h2(r2.z);
        __half2 ha3 = int_as_h2(r3.y), hb3 = int_as_h2(r3.z);
        {
            float g0 = __low2float(ha0), g1 = __high2float(ha0), g2 = __low2float(hb0);
            float2 a = __half22float2(f00), b = __half22float2(f01), c = __half22float2(f02);
            ax0 += g0 * a.x + g1 * b.x + g2 * c.x;
            ay0 += g0 * a.y + g1 * b.y + g2 * c.y;
        }
        {
            float g0 = __low2float(ha1), g1 = __high2float(ha1), g2 = __low2float(hb1);
            float2 a = __half22float2(f10), b = __half22float2(f11), c = __half22float2(f12);
            ax1 += g0 * a.x + g1 * b.x + g2 * c.x;
            ay1 += g0 * a.y + g1 * b.y + g2 * c.y;
        }
        {
            float g0 = __low2float(ha2), g1 = __high2float(ha2), g2 = __low2float(hb2);
            float2 a = __half22float2(f20), b = __half22float2(f21), c = __half22float2(f22);
            ax0 += g0 * a.x + g1 * b.x + g2 * c.x;
            ay0 += g0 * a.y + g1 * b.y + g2 * c.y;
        }
        {
            float g0 = __low2float(ha3), g1 = __high2float(ha3), g2 = __low2float(hb3);
            float2 a = __half22float2(f30), b = __half22float2(f31), c = __half22float2(f32);
            ax1 += g0 * a.x + g1 * b.x + g2 * c.x;
            ay1 += g0 * a.y + g1 * b.y + g2 * c.y;
        }
    }
    for (; j < end; ++j) {
        int4 r0 = rec[j];
        __half2 ha0 = int_as_h2(r0.y), hb0 = int_as_h2(r0.z);
        float g0 = __low2float(ha0), g1 = __high2float(ha0), g2 = __low2float(hb0);
        const __half2* p0 = reinterpret_cast<const __half2*>(hw1h + (size_t)r0.x * 256);
        float2 a = __half22float2(p0[l]);
        float2 b = __half22float2(p0[32 + l]);
        float2 c = __half22float2(p0[64 + l]);
        ax0 += g0 * a.x + g1 * b.x + g2 * c.x;
        ay0 += g0 * a.y + g1 * b.y + g2 * c.y;
    }
    float d = fmaxf((float)(end - beg), 1.0f);
    float2 root = __half22float2(
        reinterpret_cast<const __half2*>(hw1h + (size_t)node * 256 + 192)[l]);
    float2 bb = reinterpret_cast<const float2*>(b1)[l];
    float v0 = (ax0 + ax1) / d + root.x + bb.x;
    float v1 = (ay0 + ay1) / d + root.y + bb.y;
    float2 o;
    o.x = v0 > 0.f ? v0 : expm1f(v0);
    o.y = v1 > 0.f ? v1 : expm1f(v1);
    reinterpret_cast<float2*>(h2 + (size_t)node * 64)[l] = o;
}

// ---------------------------------------------------------------------------
// agg2: 8 lanes per node, lane owns c = {2l, 2l+1} via half2.
// ---------------------------------------------------------------------------
__global__ __launch_bounds__(256) void agg2_kernel(
    const int4* __restrict__ rec, const int* __restrict__ rowptr,
    const __half* __restrict__ hw2h, const float* __restrict__ b2,
    float* __restrict__ out, int N) {
    int node = (blockIdx.x * 256 + threadIdx.x) >> 3;
    int l = threadIdx.x & 7;
    if (node >= N) return;
    int beg = rowptr[node], end = rowptr[node + 1];
    float ax = 0.f, ay = 0.f;
    for (int j = beg; j < end; ++j) {
        int4 r = rec[j];
        __half2 hb = int_as_h2(r.z), hc = int_as_h2(r.w);
        float g0 = __high2float(hb), g1 = __low2float(hc), g2 = __high2float(hc);
        const __half2* p = reinterpret_cast<const __half2*>(hw2h + (size_t)r.x * 64);
        float2 f0 = __half22float2(p[l]);
        float2 f1 = __half22float2(p[8 + l]);
        float2 f2 = __half22float2(p[16 + l]);
        ax += g0 * f0.x + g1 * f1.x + g2 * f2.x;
        ay += g0 * f0.y + g1 * f1.y + g2 * f2.y;
    }
    float d = fmaxf((float)(end - beg), 1.0f);
    float2 root = __half22float2(
        reinterpret_cast<const __half2*>(hw2h + (size_t)node * 64 + 48)[l]);
    float2 bb = reinterpret_cast<const float2*>(b2)[l];
    float v0 = ax / d + root.x + bb.x;
    float v1 = ay / d + root.y + bb.y;

    float mx = fmaxf(v0, v1);
#pragma unroll
    for (int off = 4; off >= 1; off >>= 1) mx = fmaxf(mx, __shfl_xor(mx, off, 8));
    float s = __expf(v0 - mx) + __expf(v1 - mx);
#pragma unroll
    for (int off = 4; off >= 1; off >>= 1) s += __shfl_xor(s, off, 8);
    float ls = __logf(s);
    float2 o = make_float2(v0 - mx - ls, v1 - mx - ls);
    reinterpret_cast<float2*>(out + (size_t)node * 16)[l] = o;
}

// ---------------------------------------------------------------------------
extern "C" void kernel_launch(void* const* d_in, const int* in_sizes, int n_in,
                              void* d_out, int out_size, void* d_ws, size_t ws_size,
                              hipStream_t stream) {
    const float* x   = (const float*)d_in[0];
    const int*   ei  = (const int*)d_in[1];
    const float* ea  = (const float*)d_in[2];
    const float* g1  = (const float*)d_in[3];
    const float* mu1 = (const float*)d_in[4];
    const float* sg1 = (const float*)d_in[5];
    const float* r1  = (const float*)d_in[6];
    const float* b1  = (const float*)d_in[7];
    const float* g2  = (const float*)d_in[8];
    const float* mu2 = (const float*)d_in[9];
    const float* sg2 = (const float*)d_in[10];
    const float* r2  = (const float*)d_in[11];
    const float* b2  = (const float*)d_in[12];

    const int N = in_sizes[0] / 128;   // 50000
    const int E = in_sizes[2] / 2;     // 800000
    const int nbkt = (N + BKT_SIZE - 1) >> BKT_SHIFT;   // 391

    // Workspace layout
    __half* hw1h = (__half*)d_ws;                         // N*256 halves (25.6MB)
    float*  h2   = (float*)(hw1h + (size_t)N * 256);      // N*64 fp32
    __half* hw2h = (__half*)(h2 + (size_t)N * 64);        // N*64 halves
    int4*   rec  = (int4*)(hw2h + (size_t)N * 64);        // E int4 (12.8MB)
    int4*   staging = rec + E;                            // E int4 (12.8MB)
    __half* Bprep = (__half*)(staging + E);               // 32768 halves
    int*    rowptr  = (int*)(Bprep + 32768);              // N+1
    int*    bcnt    = rowptr + N + 1;                     // nbkt
    int*    bbase   = bcnt + nbkt;                        // nbkt+1
    int*    bcursor = bbase + nbkt + 1;                   // nbkt
    int*    flag    = bcursor + nbkt;                     // 1

    hipMemsetAsync(bcnt, 0, sizeof(int) * nbkt, stream);

    detect_kernel<<<1, 256, 0, stream>>>(ei, flag);
    bhist_kernel<<<(E + 4095) / 4096, 256, 0, stream>>>(ei, flag, bcnt, E, nbkt);
    bscan_kernel<<<1, 512, 0, stream>>>(bcnt, bbase, bcursor, rowptr + N, nbkt, E);

    pass1_kernel<<<(E + 8191) / 8192, 1024, 0, stream>>>(
        ei, flag, (const float2*)ea, bcursor, staging, E, nbkt);
    pass2_kernel<<<nbkt, 256, 0, stream>>>(
        staging, bbase, mu1, sg1, mu2, sg2, rec, rowptr, N);

    // Layer 1 GEMM (MFMA): x [N,128] @ [g1|root1] -> hw1h fp16 [N,256]
    bprep_kernel<<<128, 256, 0, stream>>>(g1, r1, Bprep);
    gemm1_mfma<<<dim3((N + 63) / 64, 2), 256, 0, stream>>>(x, Bprep, hw1h, N);

    agg1_kernel<<<((size_t)N * 32 + 255) / 256, 256, 0, stream>>>(
        rec, rowptr, hw1h, b1, h2, N);

    // Layer 2 GEMM: h2 [N,64] @ [g2|root2] [64,64] -> hw2h (fp16)
    gemm_cat<64, 128, 64, 48, 16>
        <<<dim3((N + 127) / 128, 1), 256, 0, stream>>>(h2, g2, r2, hw2h, N);

    agg2_kernel<<<((size_t)N * 8 + 255) / 256, 256, 0, stream>>>(
        rec, rowptr, hw2h, b2, (float*)d_out, N);
}

// Round 10
// 140.911 us; speedup vs baseline: 3.9730x; 1.0773x over previous
//
#include <hip/hip_runtime.h>
#include <hip/hip_fp16.h>

#define EPS 1e-15f
#define BKT_SHIFT 7
#define BKT_SIZE 128
#define NBKT_MAX 512

typedef _Float16 v8h __attribute__((ext_vector_type(8)));
typedef float v4f __attribute__((ext_vector_type(4)));
typedef float v2f __attribute__((ext_vector_type(2)));

#if __has_builtin(__builtin_amdgcn_cvt_pk_f32_fp8) && __has_builtin(__builtin_amdgcn_cvt_pk_fp8_f32)
#define FP8_HW 1
#else
#define FP8_HW 0
#endif

// ---------------------------------------------------------------------------
// fp8 helpers (encode in gemm1, decode in agg1 — matched paths)
// ---------------------------------------------------------------------------
__device__ __forceinline__ unsigned char f32_to_fp8(float v) {
#if FP8_HW
    int r = __builtin_amdgcn_cvt_pk_fp8_f32(v, v, 0, false);
    return (unsigned char)(r & 0xFF);
#else
    __half h = __float2half(v);
    unsigned short u; __builtin_memcpy(&u, &h, 2);
    int s = (u >> 15) << 7;
    int a = (u & 0x7FFF) + 0x40;          // RN on fp8 mantissa bit
    if (a < (9 << 10)) return (unsigned char)s;   // flush tiny to zero-code
    int t = (a >> 7) - 64;
    if (t > 126) t = 126;                 // clamp (avoid NaN code)
    return (unsigned char)(s | t);
#endif
}

__device__ __forceinline__ float2 fp8x2_to_f32(unsigned short w) {
#if FP8_HW
    v2f r = __builtin_amdgcn_cvt_pk_f32_fp8((int)w, false);
    return make_float2(r.x, r.y);
#else
    int b0 = w & 0xFF, b1 = w >> 8;
    unsigned short h0 = (unsigned short)((((b0 & 0x7F) + 64) << 7) | ((b0 & 0x80) << 8));
    unsigned short h1 = (unsigned short)((((b1 & 0x7F) + 64) << 7) | ((b1 & 0x80) << 8));
    __half x0, x1;
    __builtin_memcpy(&x0, &h0, 2);
    __builtin_memcpy(&x1, &h1, 2);
    return make_float2(__half2float(x0), __half2float(x1));
#endif
}

// ---------------------------------------------------------------------------
// Helpers
// ---------------------------------------------------------------------------
__device__ __forceinline__ int load_idx(const int* __restrict__ ei, int is64, int pos) {
    return is64 ? ei[(size_t)2 * pos] : ei[pos];
}

__device__ __forceinline__ int h2_as_int(__half2 h) {
    int w; __builtin_memcpy(&w, &h, 4); return w;
}
__device__ __forceinline__ __half2 int_as_h2(int w) {
    __half2 h; __builtin_memcpy(&h, &w, 4); return h;
}

// Detect whether edge_index arrived as int64 (odd int32 words all zero) or int32.
__global__ void detect_kernel(const int* __restrict__ ei, int* __restrict__ flag) {
    __shared__ int any_odd;
    if (threadIdx.x == 0) any_odd = 0;
    __syncthreads();
    if (ei[2 * threadIdx.x + 1] != 0) atomicOr(&any_odd, 1);
    __syncthreads();
    if (threadIdx.x == 0) *flag = any_odd ? 0 : 1;
}

// Bucket histogram: LDS-aggregated, 4096 edges/block.
__global__ __launch_bounds__(256) void bhist_kernel(
    const int* __restrict__ ei, const int* __restrict__ flag,
    int* __restrict__ bcnt, int E, int nbkt) {
    __shared__ int cnt[NBKT_MAX];
    int t = threadIdx.x;
    for (int u = t; u < nbkt; u += 256) cnt[u] = 0;
    __syncthreads();
    int is64 = *flag;
    int e0 = blockIdx.x * 4096;
#pragma unroll
    for (int i = 0; i < 16; ++i) {
        int e = e0 + i * 256 + t;
        if (e < E) atomicAdd(&cnt[load_idx(ei, is64, E + e) >> BKT_SHIFT], 1);
    }
    __syncthreads();
    for (int u = t; u < nbkt; u += 256)
        if (cnt[u]) atomicAdd(&bcnt[u], cnt[u]);
}

// Exclusive scan over bcnt[nbkt] (nbkt <= 512); also bbase[nbkt]=E, rowptr[N]=E.
__global__ void bscan_kernel(const int* __restrict__ bcnt, int* __restrict__ bbase,
                             int* __restrict__ bcursor, int* __restrict__ rowptrN,
                             int nbkt, int E) {
    __shared__ int s[512];
    int t = threadIdx.x;
    int v = (t < nbkt) ? bcnt[t] : 0;
    s[t] = v;
    __syncthreads();
    for (int o = 1; o < 512; o <<= 1) {
        int u = (t >= o) ? s[t - o] : 0;
        __syncthreads();
        s[t] += u;
        __syncthreads();
    }
    if (t < nbkt) { int ex = s[t] - v; bbase[t] = ex; bcursor[t] = ex; }
    if (t == 0) { bbase[nbkt] = E; *rowptrN = E; }
}

// ---------------------------------------------------------------------------
// Pass 1: bucket multisplit, 8192 edges per 1024-thread block, two-phase.
// ---------------------------------------------------------------------------
__global__ __launch_bounds__(1024) void pass1_kernel(
    const int* __restrict__ ei, const int* __restrict__ flag,
    const float2* __restrict__ ea, int* __restrict__ bcursor,
    int4* __restrict__ staging, int E, int nbkt) {
    __shared__ int lcnt[NBKT_MAX];
    __shared__ int lcur[NBKT_MAX];
    int t = threadIdx.x;
    if (t < nbkt) lcnt[t] = 0;
    __syncthreads();
    int is64 = *flag;
    int e0 = blockIdx.x * 8192;
    int eend = min(e0 + 8192, E);

    for (int e = e0 + t; e < eend; e += 1024)
        atomicAdd(&lcnt[load_idx(ei, is64, E + e) >> BKT_SHIFT], 1);
    __syncthreads();

    if (t < nbkt) {
        int c = lcnt[t];
        lcur[t] = c ? atomicAdd(&bcursor[t], c) : 0;
    }
    __syncthreads();

    for (int e = e0 + t; e < eend; e += 1024) {
        int src = load_idx(ei, is64, e);
        int dst = load_idx(ei, is64, E + e);
        float2 a = ea[e];
        int pos = atomicAdd(&lcur[dst >> BKT_SHIFT], 1);
        staging[pos] = make_int4(src, dst,
                                 __float_as_int(a.x), __float_as_int(a.y));
    }
}

// ---------------------------------------------------------------------------
// Pass 2: one block per bucket. Derives per-node rowptr; places records.
// ---------------------------------------------------------------------------
__global__ __launch_bounds__(256) void pass2_kernel(
    const int4* __restrict__ staging, const int* __restrict__ bbase,
    const float* __restrict__ mu1, const float* __restrict__ sg1,
    const float* __restrict__ mu2, const float* __restrict__ sg2,
    int4* __restrict__ rec, int* __restrict__ rowptr, int N) {
    __shared__ int lcnt[BKT_SIZE];
    __shared__ int ssc[BKT_SIZE];
    __shared__ int lcur[BKT_SIZE];
    int b = blockIdx.x;
    int node0 = b << BKT_SHIFT;
    int t = threadIdx.x;
    int beg = bbase[b], end = bbase[b + 1];

    if (t < BKT_SIZE) lcnt[t] = 0;
    __syncthreads();
    for (int j = beg + t; j < end; j += 256)
        atomicAdd(&lcnt[staging[j].y & (BKT_SIZE - 1)], 1);
    __syncthreads();
    int v = (t < BKT_SIZE) ? lcnt[t] : 0;
    if (t < BKT_SIZE) ssc[t] = v;
    __syncthreads();
    for (int o = 1; o < BKT_SIZE; o <<= 1) {
        int u = (t < BKT_SIZE && t >= o) ? ssc[t - o] : 0;
        __syncthreads();
        if (t < BKT_SIZE) ssc[t] += u;
        __syncthreads();
    }
    if (t < BKT_SIZE) {
        int excl = beg + ssc[t] - v;
        lcur[t] = excl;
        if (node0 + t < N) rowptr[node0 + t] = excl;
    }
    __syncthreads();

    float m1x[3], m1y[3], i1x[3], i1y[3], m2x[3], m2y[3], i2x[3], i2y[3];
#pragma unroll
    for (int k = 0; k < 3; ++k) {
        m1x[k] = mu1[2 * k]; m1y[k] = mu1[2 * k + 1];
        float s0 = sg1[2 * k], s1 = sg1[2 * k + 1];
        i1x[k] = -0.5f / (EPS + s0 * s0); i1y[k] = -0.5f / (EPS + s1 * s1);
        m2x[k] = mu2[2 * k]; m2y[k] = mu2[2 * k + 1];
        s0 = sg2[2 * k]; s1 = sg2[2 * k + 1];
        i2x[k] = -0.5f / (EPS + s0 * s0); i2y[k] = -0.5f / (EPS + s1 * s1);
    }

    for (int j = beg + t; j < end; j += 256) {
        int4 p = staging[j];
        float ax = __int_as_float(p.z), ay = __int_as_float(p.w);
        float g1v[3], g2v[3];
#pragma unroll
        for (int k = 0; k < 3; ++k) {
            float d0 = ax - m1x[k], d1 = ay - m1y[k];
            g1v[k] = __expf(d0 * d0 * i1x[k] + d1 * d1 * i1y[k]);
            d0 = ax - m2x[k]; d1 = ay - m2y[k];
            g2v[k] = __expf(d0 * d0 * i2x[k] + d1 * d1 * i2y[k]);
        }
        int pos = atomicAdd(&lcur[p.y & (BKT_SIZE - 1)], 1);
        int4 r;
        r.x = p.x;
        r.y = h2_as_int(__floats2half2_rn(g1v[0], g1v[1]));
        r.z = h2_as_int(__floats2half2_rn(g1v[2], g2v[0]));
        r.w = h2_as_int(__floats2half2_rn(g2v[1], g2v[2]));
        rec[pos] = r;
    }
}

// ---------------------------------------------------------------------------
// Bprep: fragment-ordered fp16 copy of W = [g1 | r1]  (128 x 256).
// ---------------------------------------------------------------------------
__global__ void bprep_kernel(const float* __restrict__ g1, const float* __restrict__ r1,
                             __half* __restrict__ Bprep) {
    int gid = blockIdx.x * 256 + threadIdx.x;   // 32768 total
    if (gid >= 32768) return;
    int fi = gid >> 9;
    int lane = (gid >> 3) & 63;
    int i = gid & 7;
    int ks = fi & 3, cb = fi >> 2;
    int k = ks * 32 + (lane >> 4) * 8 + i;
    int c = cb * 16 + (lane & 15);
    float v = (c < 192) ? g1[k * 192 + c] : r1[k * 64 + (c - 192)];
    Bprep[gid] = __float2half(v);
}

// ---------------------------------------------------------------------------
// Layer-1 GEMM via MFMA f16: x [M,128] fp32 -> hw1k fp8 [M,192] + hw1r fp16 [M,64].
// BM=64, BN=128: grid (ceil(M/64), 2). Coalesced A staging, swizzled LDS.
// ---------------------------------------------------------------------------
__global__ __launch_bounds__(256) void gemm1_mfma(
    const float* __restrict__ A, const __half* __restrict__ Bprep,
    unsigned char* __restrict__ hw1k, __half* __restrict__ hw1r, int M) {
    __shared__ char a_lds[64 * 256];   // 64 rows x 128 fp16, XOR-swizzled
    int row0 = blockIdx.x * 64;
    int tid = threadIdx.x;
    int wid = tid >> 6, lane = tid & 63;

    const float4* xf4 = reinterpret_cast<const float4*>(A);
#pragma unroll
    for (int j = 0; j < 8; ++j) {
        int g = j * 256 + tid;
        int r = g >> 5, c = g & 31;
        int gr = row0 + r;
        float4 f = (gr < M) ? xf4[(size_t)gr * 32 + c]
                            : make_float4(0.f, 0.f, 0.f, 0.f);
        int2 v;
        v.x = h2_as_int(__floats2half2_rn(f.x, f.y));
        v.y = h2_as_int(__floats2half2_rn(f.z, f.w));
        int byte = r * 256 + c * 8;
        byte ^= (r & 7) << 4;
        *reinterpret_cast<int2*>(&a_lds[byte]) = v;
    }

    v8h bf[2][4];   // [cf][ks]
#pragma unroll
    for (int cf = 0; cf < 2; ++cf)
#pragma unroll
        for (int ks = 0; ks < 4; ++ks) {
            int cb = blockIdx.y * 8 + wid * 2 + cf;
            int fi = cb * 4 + ks;
            bf[cf][ks] = *reinterpret_cast<const v8h*>(Bprep + (size_t)fi * 512 + lane * 8);
        }

    __syncthreads();

    v4f acc[4][2] = {};
#pragma unroll
    for (int ks = 0; ks < 4; ++ks) {
        v8h af[4];
#pragma unroll
        for (int rf = 0; rf < 4; ++rf) {
            int r = rf * 16 + (lane & 15);
            int byte = r * 256 + ks * 64 + (lane >> 4) * 16;
            byte ^= (r & 7) << 4;
            af[rf] = *reinterpret_cast<const v8h*>(&a_lds[byte]);
        }
#pragma unroll
        for (int rf = 0; rf < 4; ++rf)
#pragma unroll
            for (int cf = 0; cf < 2; ++cf)
                acc[rf][cf] = __builtin_amdgcn_mfma_f32_16x16x32_f16(
                    af[rf], bf[cf][ks], acc[rf][cf], 0, 0, 0);
    }

#pragma unroll
    for (int rf = 0; rf < 4; ++rf)
#pragma unroll
        for (int cf = 0; cf < 2; ++cf) {
            int gc = blockIdx.y * 128 + wid * 32 + cf * 16 + (lane & 15);
#pragma unroll
            for (int i = 0; i < 4; ++i) {
                int gr = row0 + rf * 16 + (lane >> 4) * 4 + i;
                if (gr < M) {
                    float val = acc[rf][cf][i];
                    if (gc < 192)
                        hw1k[(size_t)gr * 192 + gc] = f32_to_fp8(val);
                    else
                        hw1r[(size_t)gr * 64 + (gc - 192)] = __float2half(val);
                }
            }
        }
}

// ---------------------------------------------------------------------------
// Vector GEMM (layer 2): Cout[n,c] = A[n,:] @ [W1|W2], fp16 out.
// ---------------------------------------------------------------------------
template<int K, int TN, int TC, int C1, int C2>
__global__ __launch_bounds__(256) void gemm_cat(
    const float* __restrict__ A, const float* __restrict__ W1,
    const float* __restrict__ W2, __half* __restrict__ Cout, int nrows) {
    constexpr int NT = TN / 8;
    constexpr int CT = TC / 4;
    static_assert(NT * CT == 256, "bad tile");
    constexpr int COLS = C1 + C2;
    __shared__ float xs[TN][K + 4];

    int row0 = blockIdx.x * TN;
    int col0 = blockIdx.y * TC;

    constexpr int NV = TN * (K / 4);
    for (int id = threadIdx.x; id < NV; id += 256) {
        int r  = id / (K / 4);
        int k4 = id % (K / 4);
        int gr = row0 + r;
        float4 v = make_float4(0.f, 0.f, 0.f, 0.f);
        if (gr < nrows) v = reinterpret_cast<const float4*>(A + (size_t)gr * K)[k4];
        *reinterpret_cast<float4*>(&xs[r][4 * k4]) = v;
    }
    __syncthreads();

    int ct = threadIdx.x % CT;
    int nt = threadIdx.x / CT;
    int c0 = col0 + ct * 4;

    const float* wp;
    int wstride;
    if (c0 < C1) { wp = W1 + c0;        wstride = C1; }
    else         { wp = W2 + (c0 - C1); wstride = C2; }

    float acc[8][4] = {};
#pragma unroll 4
    for (int k = 0; k < K; ++k) {
        float4 w = *reinterpret_cast<const float4*>(wp + (size_t)k * wstride);
        float xr[8];
#pragma unroll
        for (int i = 0; i < 8; ++i) xr[i] = xs[nt * 8 + i][k];
#pragma unroll
        for (int i = 0; i < 8; ++i) {
            acc[i][0] += xr[i] * w.x;
            acc[i][1] += xr[i] * w.y;
            acc[i][2] += xr[i] * w.z;
            acc[i][3] += xr[i] * w.w;
        }
    }

#pragma unroll
    for (int i = 0; i < 8; ++i) {
        int gr = row0 + nt * 8 + i;
        if (gr < nrows) {
            __half2* p = reinterpret_cast<__half2*>(Cout + (size_t)gr * COLS + c0);
            p[0] = __floats2half2_rn(acc[i][0], acc[i][1]);
            p[1] = __floats2half2_rn(acc[i][2], acc[i][3]);
        }
    }
}

// ---------------------------------------------------------------------------
// agg1: 32 lanes per node, lane owns m = {2l, 2l+1}; fp8 gather table, unroll 4.
// hw1k [N][192] fp8: col k*64+m. hw1r [N][64] fp16 root.
// ---------------------------------------------------------------------------
__global__ __launch_bounds__(256) void agg1_kernel(
    const int4* __restrict__ rec, const int* __restrict__ rowptr,
    const unsigned char* __restrict__ hw1k, const __half* __restrict__ hw1r,
    const float* __restrict__ b1, float* __restrict__ h2, int N) {
    int node = (blockIdx.x * 256 + threadIdx.x) >> 5;
    int l = threadIdx.x & 31;
    if (node >= N) return;
    int beg = rowptr[node], end = rowptr[node + 1];
    float ax0 = 0.f, ay0 = 0.f, ax1 = 0.f, ay1 = 0.f;
    int j = beg;
    for (; j + 3 < end; j += 4) {
        int4 r0 = rec[j], r1 = rec[j + 1], r2 = rec[j + 2], r3 = rec[j + 3];
        const unsigned short* p0 = reinterpret_cast<const unsigned short*>(
            hw1k + (size_t)r0.x * 192);
        const unsigned short* p1 = reinterpret_cast<const unsigned short*>(
            hw1k + (size_t)r1.x * 192);
        const unsigned short* p2 = reinterpret_cast<const unsigned short*>(
            hw1k + (size_t)r2.x * 192);
        const unsigned short* p3 = reinterpret_cast<const unsigned short*>(
            hw1k + (size_t)r3.x * 192);
        unsigned short w00 = p0[l], w01 = p0[32 + l], w02 = p0[64 + l];
        unsigned short w10 = p1[l], w11 = p1[32 + l], w12 = p1[64 + l];
        unsigned short w20 = p2[l], w21 = p2[32 + l], w22 = p2[64 + l];
        unsigned short w30 = p3[l], w31 = p3[32 + l], w32 = p3[64 + l];
        __half2 ha0 = int_as_h2(r0.y), hb0 = int_as_h2(r0.z);
        __half2 ha1 = int_as_h2(r1.y), hb1 = int_as_h2(r1.z);
        __half2 ha2 = int_as_h2(r2.y), hb2 = int_as_h2(r2.z);
        __half2 ha3 = int_as_h2(r3.y), hb3 = int_as_h2(r3.z);
        {
            float g0 = __low2float(ha0), g1 = __high2float(ha0), g2 = __low2float(hb0);
            float2 a = fp8x2_to_f32(w00), b = fp8x2_to_f32(w01), c = fp8x2_to_f32(w02);
            ax0 += g0 * a.x + g1 * b.x + g2 * c.x;
            ay0 += g0 * a.y + g1 * b.y + g2 * c.y;
        }
        {
            float g0 = __low2float(ha1), g1 = __high2float(ha1), g2 = __low2float(hb1);
            float2 a = fp8x2_to_f32(w10), b = fp8x2_to_f32(w11), c = fp8x2_to_f32(w12);
            ax1 += g0 * a.x + g1 * b.x + g2 * c.x;
            ay1 += g0 * a.y + g1 * b.y + g2 * c.y;
        }
        {
            float g0 = __low2float(ha2), g1 = __high2float(ha2), g2 = __low2float(hb2);
            float2 a = fp8x2_to_f32(w20), b = fp8x2_to_f32(w21), c = fp8x2_to_f32(w22);
            ax0 += g0 * a.x + g1 * b.x + g2 * c.x;
            ay0 += g0 * a.y + g1 * b.y + g2 * c.y;
        }
        {
            float g0 = __low2float(ha3), g1 = __high2float(ha3), g2 = __low2float(hb3);
            float2 a = fp8x2_to_f32(w30), b = fp8x2_to_f32(w31), c = fp8x2_to_f32(w32);
            ax1 += g0 * a.x + g1 * b.x + g2 * c.x;
            ay1 += g0 * a.y + g1 * b.y + g2 * c.y;
        }
    }
    for (; j < end; ++j) {
        int4 r0 = rec[j];
        __half2 ha0 = int_as_h2(r0.y), hb0 = int_as_h2(r0.z);
        float g0 = __low2float(ha0), g1 = __high2float(ha0), g2 = __low2float(hb0);
        const unsigned short* p0 = reinterpret_cast<const unsigned short*>(
            hw1k + (size_t)r0.x * 192);
        float2 a = fp8x2_to_f32(p0[l]);
        float2 b = fp8x2_to_f32(p0[32 + l]);
        float2 c = fp8x2_to_f32(p0[64 + l]);
        ax0 += g0 * a.x + g1 * b.x + g2 * c.x;
        ay0 += g0 * a.y + g1 * b.y + g2 * c.y;
    }
    float d = fmaxf((float)(end - beg), 1.0f);
    float2 root = __half22float2(
        reinterpret_cast<const __half2*>(hw1r + (size_t)node * 64)[l]);
    float2 bb = reinterpret_cast<const float2*>(b1)[l];
    float v0 = (ax0 + ax1) / d + root.x + bb.x;
    float v1 = (ay0 + ay1) / d + root.y + bb.y;
    float2 o;
    o.x = v0 > 0.f ? v0 : expm1f(v0);
    o.y = v1 > 0.f ? v1 : expm1f(v1);
    reinterpret_cast<float2*>(h2 + (size_t)node * 64)[l] = o;
}

// ---------------------------------------------------------------------------
// agg2: 8 lanes per node, lane owns c = {2l, 2l+1} via half2.
// ---------------------------------------------------------------------------
__global__ __launch_bounds__(256) void agg2_kernel(
    const int4* __restrict__ rec, const int* __restrict__ rowptr,
    const __half* __restrict__ hw2h, const float* __restrict__ b2,
    float* __restrict__ out, int N) {
    int node = (blockIdx.x * 256 + threadIdx.x) >> 3;
    int l = threadIdx.x & 7;
    if (node >= N) return;
    int beg = rowptr[node], end = rowptr[node + 1];
    float ax = 0.f, ay = 0.f;
    for (int j = beg; j < end; ++j) {
        int4 r = rec[j];
        __half2 hb = int_as_h2(r.z), hc = int_as_h2(r.w);
        float g0 = __high2float(hb), g1 = __low2float(hc), g2 = __high2float(hc);
        const __half2* p = reinterpret_cast<const __half2*>(hw2h + (size_t)r.x * 64);
        float2 f0 = __half22float2(p[l]);
        float2 f1 = __half22float2(p[8 + l]);
        float2 f2 = __half22float2(p[16 + l]);
        ax += g0 * f0.x + g1 * f1.x + g2 * f2.x;
        ay += g0 * f0.y + g1 * f1.y + g2 * f2.y;
    }
    float d = fmaxf((float)(end - beg), 1.0f);
    float2 root = __half22float2(
        reinterpret_cast<const __half2*>(hw2h + (size_t)node * 64 + 48)[l]);
    float2 bb = reinterpret_cast<const float2*>(b2)[l];
    float v0 = ax / d + root.x + bb.x;
    float v1 = ay / d + root.y + bb.y;

    float mx = fmaxf(v0, v1);
#pragma unroll
    for (int off = 4; off >= 1; off >>= 1) mx = fmaxf(mx, __shfl_xor(mx, off, 8));
    float s = __expf(v0 - mx) + __expf(v1 - mx);
#pragma unroll
    for (int off = 4; off >= 1; off >>= 1) s += __shfl_xor(s, off, 8);
    float ls = __logf(s);
    float2 o = make_float2(v0 - mx - ls, v1 - mx - ls);
    reinterpret_cast<float2*>(out + (size_t)node * 16)[l] = o;
}

// ---------------------------------------------------------------------------
extern "C" void kernel_launch(void* const* d_in, const int* in_sizes, int n_in,
                              void* d_out, int out_size, void* d_ws, size_t ws_size,
                              hipStream_t stream) {
    const float* x   = (const float*)d_in[0];
    const int*   ei  = (const int*)d_in[1];
    const float* ea  = (const float*)d_in[2];
    const float* g1  = (const float*)d_in[3];
    const float* mu1 = (const float*)d_in[4];
    const float* sg1 = (const float*)d_in[5];
    const float* r1  = (const float*)d_in[6];
    const float* b1  = (const float*)d_in[7];
    const float* g2  = (const float*)d_in[8];
    const float* mu2 = (const float*)d_in[9];
    const float* sg2 = (const float*)d_in[10];
    const float* r2  = (const float*)d_in[11];
    const float* b2  = (const float*)d_in[12];

    const int N = in_sizes[0] / 128;   // 50000
    const int E = in_sizes[2] / 2;     // 800000
    const int nbkt = (N + BKT_SIZE - 1) >> BKT_SHIFT;   // 391

    // Workspace layout
    unsigned char* hw1k = (unsigned char*)d_ws;           // N*192 fp8 (9.6MB)
    __half* hw1r = (__half*)(hw1k + (size_t)N * 192);     // N*64 fp16
    float*  h2   = (float*)(hw1r + (size_t)N * 64);       // N*64 fp32
    __half* hw2h = (__half*)(h2 + (size_t)N * 64);        // N*64 fp16
    int4*   rec  = (int4*)(hw2h + (size_t)N * 64);        // E int4 (12.8MB)
    int4*   staging = rec + E;                            // E int4 (12.8MB)
    __half* Bprep = (__half*)(staging + E);               // 32768 halves
    int*    rowptr  = (int*)(Bprep + 32768);              // N+1
    int*    bcnt    = rowptr + N + 1;                     // nbkt
    int*    bbase   = bcnt + nbkt;                        // nbkt+1
    int*    bcursor = bbase + nbkt + 1;                   // nbkt
    int*    flag    = bcursor + nbkt;                     // 1

    hipMemsetAsync(bcnt, 0, sizeof(int) * nbkt, stream);

    detect_kernel<<<1, 256, 0, stream>>>(ei, flag);
    bhist_kernel<<<(E + 4095) / 4096, 256, 0, stream>>>(ei, flag, bcnt, E, nbkt);
    bscan_kernel<<<1, 512, 0, stream>>>(bcnt, bbase, bcursor, rowptr + N, nbkt, E);

    pass1_kernel<<<(E + 8191) / 8192, 1024, 0, stream>>>(
        ei, flag, (const float2*)ea, bcursor, staging, E, nbkt);
    pass2_kernel<<<nbkt, 256, 0, stream>>>(
        staging, bbase, mu1, sg1, mu2, sg2, rec, rowptr, N);

    // Layer 1 GEMM (MFMA): x [N,128] @ [g1|root1] -> hw1k fp8 + hw1r fp16
    bprep_kernel<<<128, 256, 0, stream>>>(g1, r1, Bprep);
    gemm1_mfma<<<dim3((N + 63) / 64, 2), 256, 0, stream>>>(x, Bprep, hw1k, hw1r, N);

    agg1_kernel<<<((size_t)N * 32 + 255) / 256, 256, 0, stream>>>(
        rec, rowptr, hw1k, hw1r, b1, h2, N);

    // Layer 2 GEMM: h2 [N,64] @ [g2|root2] [64,64] -> hw2h (fp16)
    gemm_cat<64, 128, 64, 48, 16>
        <<<dim3((N + 127) / 128, 1), 256, 0, stream>>>(h2, g2, r2, hw2h, N);

    agg2_kernel<<<((size_t)N * 8 + 255) / 256, 256, 0, stream>>>(
        rec, rowptr, hw2h, b2, (float*)d_out, N);
}

// Round 11
// 135.931 us; speedup vs baseline: 4.1186x; 1.0366x over previous
//
#include <hip/hip_runtime.h>
#include <hip/hip_fp16.h>

#define EPS 1e-15f
#define BKT_SHIFT 7
#define BKT_SIZE 128
#define NBKT_MAX 512

typedef _Float16 v8h __attribute__((ext_vector_type(8)));
typedef float v4f __attribute__((ext_vector_type(4)));
typedef float v2f __attribute__((ext_vector_type(2)));

#if __has_builtin(__builtin_amdgcn_cvt_pk_f32_fp8) && __has_builtin(__builtin_amdgcn_cvt_pk_fp8_f32)
#define FP8_HW 1
#else
#define FP8_HW 0
#endif

// ---------------------------------------------------------------------------
// fp8 helpers (encode in gemm1, decode in agg1 — matched paths)
// ---------------------------------------------------------------------------
__device__ __forceinline__ unsigned char f32_to_fp8(float v) {
#if FP8_HW
    int r = __builtin_amdgcn_cvt_pk_fp8_f32(v, v, 0, false);
    return (unsigned char)(r & 0xFF);
#else
    __half h = __float2half(v);
    unsigned short u; __builtin_memcpy(&u, &h, 2);
    int s = (u >> 15) << 7;
    int a = (u & 0x7FFF) + 0x40;          // RN on fp8 mantissa bit
    if (a < (9 << 10)) return (unsigned char)s;   // flush tiny to zero-code
    int t = (a >> 7) - 64;
    if (t > 126) t = 126;                 // clamp (avoid NaN code)
    return (unsigned char)(s | t);
#endif
}

__device__ __forceinline__ float2 fp8x2_to_f32(unsigned short w) {
#if FP8_HW
    v2f r = __builtin_amdgcn_cvt_pk_f32_fp8((int)w, false);
    return make_float2(r.x, r.y);
#else
    int b0 = w & 0xFF, b1 = w >> 8;
    unsigned short h0 = (unsigned short)((((b0 & 0x7F) + 64) << 7) | ((b0 & 0x80) << 8));
    unsigned short h1 = (unsigned short)((((b1 & 0x7F) + 64) << 7) | ((b1 & 0x80) << 8));
    __half x0, x1;
    __builtin_memcpy(&x0, &h0, 2);
    __builtin_memcpy(&x1, &h1, 2);
    return make_float2(__half2float(x0), __half2float(x1));
#endif
}

// ---------------------------------------------------------------------------
// Helpers
// ---------------------------------------------------------------------------
__device__ __forceinline__ int load_idx(const int* __restrict__ ei, int is64, int pos) {
    return is64 ? ei[(size_t)2 * pos] : ei[pos];
}

__device__ __forceinline__ int h2_as_int(__half2 h) {
    int w; __builtin_memcpy(&w, &h, 4); return w;
}
__device__ __forceinline__ __half2 int_as_h2(int w) {
    __half2 h; __builtin_memcpy(&h, &w, 4); return h;
}

// Detect int64 vs int32 edge_index; ALSO zeroes bcnt (replaces the runtime's
// fillBufferAligned blit which cost ~41us of serialized graph time).
__global__ void detect_kernel(const int* __restrict__ ei, int* __restrict__ flag,
                              int* __restrict__ bcnt, int nbkt) {
    __shared__ int any_odd;
    if (threadIdx.x == 0) any_odd = 0;
    __syncthreads();
    for (int u = threadIdx.x; u < nbkt; u += 256) bcnt[u] = 0;
    if (ei[2 * threadIdx.x + 1] != 0) atomicOr(&any_odd, 1);
    __syncthreads();
    if (threadIdx.x == 0) *flag = any_odd ? 0 : 1;
}

// Bucket histogram: LDS-aggregated, 4096 edges/block.
__global__ __launch_bounds__(256) void bhist_kernel(
    const int* __restrict__ ei, const int* __restrict__ flag,
    int* __restrict__ bcnt, int E, int nbkt) {
    __shared__ int cnt[NBKT_MAX];
    int t = threadIdx.x;
    for (int u = t; u < nbkt; u += 256) cnt[u] = 0;
    __syncthreads();
    int is64 = *flag;
    int e0 = blockIdx.x * 4096;
#pragma unroll
    for (int i = 0; i < 16; ++i) {
        int e = e0 + i * 256 + t;
        if (e < E) atomicAdd(&cnt[load_idx(ei, is64, E + e) >> BKT_SHIFT], 1);
    }
    __syncthreads();
    for (int u = t; u < nbkt; u += 256)
        if (cnt[u]) atomicAdd(&bcnt[u], cnt[u]);
}

// Exclusive scan over bcnt[nbkt] (nbkt <= 512); also bbase[nbkt]=E, rowptr[N]=E.
__global__ void bscan_kernel(const int* __restrict__ bcnt, int* __restrict__ bbase,
                             int* __restrict__ bcursor, int* __restrict__ rowptrN,
                             int nbkt, int E) {
    __shared__ int s[512];
    int t = threadIdx.x;
    int v = (t < nbkt) ? bcnt[t] : 0;
    s[t] = v;
    __syncthreads();
    for (int o = 1; o < 512; o <<= 1) {
        int u = (t >= o) ? s[t - o] : 0;
        __syncthreads();
        s[t] += u;
        __syncthreads();
    }
    if (t < nbkt) { int ex = s[t] - v; bbase[t] = ex; bcursor[t] = ex; }
    if (t == 0) { bbase[nbkt] = E; *rowptrN = E; }
}

// ---------------------------------------------------------------------------
// Pass 1: bucket multisplit, 8192 edges per 1024-thread block, two-phase.
// ---------------------------------------------------------------------------
__global__ __launch_bounds__(1024) void pass1_kernel(
    const int* __restrict__ ei, const int* __restrict__ flag,
    const float2* __restrict__ ea, int* __restrict__ bcursor,
    int4* __restrict__ staging, int E, int nbkt) {
    __shared__ int lcnt[NBKT_MAX];
    __shared__ int lcur[NBKT_MAX];
    int t = threadIdx.x;
    if (t < nbkt) lcnt[t] = 0;
    __syncthreads();
    int is64 = *flag;
    int e0 = blockIdx.x * 8192;
    int eend = min(e0 + 8192, E);

    for (int e = e0 + t; e < eend; e += 1024)
        atomicAdd(&lcnt[load_idx(ei, is64, E + e) >> BKT_SHIFT], 1);
    __syncthreads();

    if (t < nbkt) {
        int c = lcnt[t];
        lcur[t] = c ? atomicAdd(&bcursor[t], c) : 0;
    }
    __syncthreads();

    for (int e = e0 + t; e < eend; e += 1024) {
        int src = load_idx(ei, is64, e);
        int dst = load_idx(ei, is64, E + e);
        float2 a = ea[e];
        int pos = atomicAdd(&lcur[dst >> BKT_SHIFT], 1);
        staging[pos] = make_int4(src, dst,
                                 __float_as_int(a.x), __float_as_int(a.y));
    }
}

// ---------------------------------------------------------------------------
// Pass 2: one block per bucket. Derives per-node rowptr; places records.
// ---------------------------------------------------------------------------
__global__ __launch_bounds__(256) void pass2_kernel(
    const int4* __restrict__ staging, const int* __restrict__ bbase,
    const float* __restrict__ mu1, const float* __restrict__ sg1,
    const float* __restrict__ mu2, const float* __restrict__ sg2,
    int4* __restrict__ rec, int* __restrict__ rowptr, int N) {
    __shared__ int lcnt[BKT_SIZE];
    __shared__ int ssc[BKT_SIZE];
    __shared__ int lcur[BKT_SIZE];
    int b = blockIdx.x;
    int node0 = b << BKT_SHIFT;
    int t = threadIdx.x;
    int beg = bbase[b], end = bbase[b + 1];

    if (t < BKT_SIZE) lcnt[t] = 0;
    __syncthreads();
    for (int j = beg + t; j < end; j += 256)
        atomicAdd(&lcnt[staging[j].y & (BKT_SIZE - 1)], 1);
    __syncthreads();
    int v = (t < BKT_SIZE) ? lcnt[t] : 0;
    if (t < BKT_SIZE) ssc[t] = v;
    __syncthreads();
    for (int o = 1; o < BKT_SIZE; o <<= 1) {
        int u = (t < BKT_SIZE && t >= o) ? ssc[t - o] : 0;
        __syncthreads();
        if (t < BKT_SIZE) ssc[t] += u;
        __syncthreads();
    }
    if (t < BKT_SIZE) {
        int excl = beg + ssc[t] - v;
        lcur[t] = excl;
        if (node0 + t < N) rowptr[node0 + t] = excl;
    }
    __syncthreads();

    float m1x[3], m1y[3], i1x[3], i1y[3], m2x[3], m2y[3], i2x[3], i2y[3];
#pragma unroll
    for (int k = 0; k < 3; ++k) {
        m1x[k] = mu1[2 * k]; m1y[k] = mu1[2 * k + 1];
        float s0 = sg1[2 * k], s1 = sg1[2 * k + 1];
        i1x[k] = -0.5f / (EPS + s0 * s0); i1y[k] = -0.5f / (EPS + s1 * s1);
        m2x[k] = mu2[2 * k]; m2y[k] = mu2[2 * k + 1];
        s0 = sg2[2 * k]; s1 = sg2[2 * k + 1];
        i2x[k] = -0.5f / (EPS + s0 * s0); i2y[k] = -0.5f / (EPS + s1 * s1);
    }

    for (int j = beg + t; j < end; j += 256) {
        int4 p = staging[j];
        float ax = __int_as_float(p.z), ay = __int_as_float(p.w);
        float g1v[3], g2v[3];
#pragma unroll
        for (int k = 0; k < 3; ++k) {
            float d0 = ax - m1x[k], d1 = ay - m1y[k];
            g1v[k] = __expf(d0 * d0 * i1x[k] + d1 * d1 * i1y[k]);
            d0 = ax - m2x[k]; d1 = ay - m2y[k];
            g2v[k] = __expf(d0 * d0 * i2x[k] + d1 * d1 * i2y[k]);
        }
        int pos = atomicAdd(&lcur[p.y & (BKT_SIZE - 1)], 1);
        int4 r;
        r.x = p.x;
        r.y = h2_as_int(__floats2half2_rn(g1v[0], g1v[1]));
        r.z = h2_as_int(__floats2half2_rn(g1v[2], g2v[0]));
        r.w = h2_as_int(__floats2half2_rn(g2v[1], g2v[2]));
        rec[pos] = r;
    }
}

// ---------------------------------------------------------------------------
// Bprep: fragment-ordered fp16 copy of W = [g1 | r1]  (128 x 256).
// ---------------------------------------------------------------------------
__global__ void bprep_kernel(const float* __restrict__ g1, const float* __restrict__ r1,
                             __half* __restrict__ Bprep) {
    int gid = blockIdx.x * 256 + threadIdx.x;   // 32768 total
    if (gid >= 32768) return;
    int fi = gid >> 9;
    int lane = (gid >> 3) & 63;
    int i = gid & 7;
    int ks = fi & 3, cb = fi >> 2;
    int k = ks * 32 + (lane >> 4) * 8 + i;
    int c = cb * 16 + (lane & 15);
    float v = (c < 192) ? g1[k * 192 + c] : r1[k * 64 + (c - 192)];
    Bprep[gid] = __float2half(v);
}

// ---------------------------------------------------------------------------
// Layer-1 GEMM via MFMA f16: x [M,128] fp32 -> hw1k fp8 [M,192] + hw1r fp16 [M,64].
// BM=64, BN=128: grid (ceil(M/64), 2). Coalesced A staging, swizzled LDS.
// ---------------------------------------------------------------------------
__global__ __launch_bounds__(256) void gemm1_mfma(
    const float* __restrict__ A, const __half* __restrict__ Bprep,
    unsigned char* __restrict__ hw1k, __half* __restrict__ hw1r, int M) {
    __shared__ char a_lds[64 * 256];   // 64 rows x 128 fp16, XOR-swizzled
    int row0 = blockIdx.x * 64;
    int tid = threadIdx.x;
    int wid = tid >> 6, lane = tid & 63;

    const float4* xf4 = reinterpret_cast<const float4*>(A);
#pragma unroll
    for (int j = 0; j < 8; ++j) {
        int g = j * 256 + tid;
        int r = g >> 5, c = g & 31;
        int gr = row0 + r;
        float4 f = (gr < M) ? xf4[(size_t)gr * 32 + c]
                            : make_float4(0.f, 0.f, 0.f, 0.f);
        int2 v;
        v.x = h2_as_int(__floats2half2_rn(f.x, f.y));
        v.y = h2_as_int(__floats2half2_rn(f.z, f.w));
        int byte = r * 256 + c * 8;
        byte ^= (r & 7) << 4;
        *reinterpret_cast<int2*>(&a_lds[byte]) = v;
    }

    v8h bf[2][4];   // [cf][ks]
#pragma unroll
    for (int cf = 0; cf < 2; ++cf)
#pragma unroll
        for (int ks = 0; ks < 4; ++ks) {
            int cb = blockIdx.y * 8 + wid * 2 + cf;
            int fi = cb * 4 + ks;
            bf[cf][ks] = *reinterpret_cast<const v8h*>(Bprep + (size_t)fi * 512 + lane * 8);
        }

    __syncthreads();

    v4f acc[4][2] = {};
#pragma unroll
    for (int ks = 0; ks < 4; ++ks) {
        v8h af[4];
#pragma unroll
        for (int rf = 0; rf < 4; ++rf) {
            int r = rf * 16 + (lane & 15);
            int byte = r * 256 + ks * 64 + (lane >> 4) * 16;
            byte ^= (r & 7) << 4;
            af[rf] = *reinterpret_cast<const v8h*>(&a_lds[byte]);
        }
#pragma unroll
        for (int rf = 0; rf < 4; ++rf)
#pragma unroll
            for (int cf = 0; cf < 2; ++cf)
                acc[rf][cf] = __builtin_amdgcn_mfma_f32_16x16x32_f16(
                    af[rf], bf[cf][ks], acc[rf][cf], 0, 0, 0);
    }

#pragma unroll
    for (int rf = 0; rf < 4; ++rf)
#pragma unroll
        for (int cf = 0; cf < 2; ++cf) {
            int gc = blockIdx.y * 128 + wid * 32 + cf * 16 + (lane & 15);
#pragma unroll
            for (int i = 0; i < 4; ++i) {
                int gr = row0 + rf * 16 + (lane >> 4) * 4 + i;
                if (gr < M) {
                    float val = acc[rf][cf][i];
                    if (gc < 192)
                        hw1k[(size_t)gr * 192 + gc] = f32_to_fp8(val);
                    else
                        hw1r[(size_t)gr * 64 + (gc - 192)] = __float2half(val);
                }
            }
        }
}

// ---------------------------------------------------------------------------
// Vector GEMM (layer 2): Cout[n,c] = A[n,:] @ [W1|W2], fp16 out.
// ---------------------------------------------------------------------------
template<int K, int TN, int TC, int C1, int C2>
__global__ __launch_bounds__(256) void gemm_cat(
    const float* __restrict__ A, const float* __restrict__ W1,
    const float* __restrict__ W2, __half* __restrict__ Cout, int nrows) {
    constexpr int NT = TN / 8;
    constexpr int CT = TC / 4;
    static_assert(NT * CT == 256, "bad tile");
    constexpr int COLS = C1 + C2;
    __shared__ float xs[TN][K + 4];

    int row0 = blockIdx.x * TN;
    int col0 = blockIdx.y * TC;

    constexpr int NV = TN * (K / 4);
    for (int id = threadIdx.x; id < NV; id += 256) {
        int r  = id / (K / 4);
        int k4 = id % (K / 4);
        int gr = row0 + r;
        float4 v = make_float4(0.f, 0.f, 0.f, 0.f);
        if (gr < nrows) v = reinterpret_cast<const float4*>(A + (size_t)gr * K)[k4];
        *reinterpret_cast<float4*>(&xs[r][4 * k4]) = v;
    }
    __syncthreads();

    int ct = threadIdx.x % CT;
    int nt = threadIdx.x / CT;
    int c0 = col0 + ct * 4;

    const float* wp;
    int wstride;
    if (c0 < C1) { wp = W1 + c0;        wstride = C1; }
    else         { wp = W2 + (c0 - C1); wstride = C2; }

    float acc[8][4] = {};
#pragma unroll 4
    for (int k = 0; k < K; ++k) {
        float4 w = *reinterpret_cast<const float4*>(wp + (size_t)k * wstride);
        float xr[8];
#pragma unroll
        for (int i = 0; i < 8; ++i) xr[i] = xs[nt * 8 + i][k];
#pragma unroll
        for (int i = 0; i < 8; ++i) {
            acc[i][0] += xr[i] * w.x;
            acc[i][1] += xr[i] * w.y;
            acc[i][2] += xr[i] * w.z;
            acc[i][3] += xr[i] * w.w;
        }
    }

#pragma unroll
    for (int i = 0; i < 8; ++i) {
        int gr = row0 + nt * 8 + i;
        if (gr < nrows) {
            __half2* p = reinterpret_cast<__half2*>(Cout + (size_t)gr * COLS + c0);
            p[0] = __floats2half2_rn(acc[i][0], acc[i][1]);
            p[1] = __floats2half2_rn(acc[i][2], acc[i][3]);
        }
    }
}

// ---------------------------------------------------------------------------
// agg1: 32 lanes per node, lane owns m = {2l, 2l+1}; fp8 gather table, unroll 4.
// hw1k [N][192] fp8: col k*64+m. hw1r [N][64] fp16 root.
// ---------------------------------------------------------------------------
__global__ __launch_bounds__(256) void agg1_kernel(
    const int4* __restrict__ rec, const int* __restrict__ rowptr,
    const unsigned char* __restrict__ hw1k, const __half* __restrict__ hw1r,
    const float* __restrict__ b1, float* __restrict__ h2, int N) {
    int node = (blockIdx.x * 256 + threadIdx.x) >> 5;
    int l = threadIdx.x & 31;
    if (node >= N) return;
    int beg = rowptr[node], end = rowptr[node + 1];
    float ax0 = 0.f, ay0 = 0.f, ax1 = 0.f, ay1 = 0.f;
    int j = beg;
    for (; j + 3 < end; j += 4) {
        int4 r0 = rec[j], r1 = rec[j + 1], r2 = rec[j + 2], r3 = rec[j + 3];
        const unsigned short* p0 = reinterpret_cast<const unsigned short*>(
            hw1k + (size_t)r0.x * 192);
        const unsigned short* p1 = reinterpret_cast<const unsigned short*>(
            hw1k + (size_t)r1.x * 192);
        const unsigned short* p2 = reinterpret_cast<const unsigned short*>(
            hw1k + (size_t)r2.x * 192);
        const unsigned short* p3 = reinterpret_cast<const unsigned short*>(
            hw1k + (size_t)r3.x * 192);
        unsigned short w00 = p0[l], w01 = p0[32 + l], w02 = p0[64 + l];
        unsigned short w10 = p1[l], w11 = p1[32 + l], w12 = p1[64 + l];
        unsigned short w20 = p2[l], w21 = p2[32 + l], w22 = p2[64 + l];
        unsigned short w30 = p3[l], w31 = p3[32 + l], w32 = p3[64 + l];
        __half2 ha0 = int_as_h2(r0.y), hb0 = int_as_h2(r0.z);
        __half2 ha1 = int_as_h2(r1.y), hb1 = int_as_h2(r1.z);
        __half2 ha2 = int_as_h2(r2.y), hb2 = int_as_h2(r2.z);
        __half2 ha3 = int_as_h2(r3.y), hb3 = int_as_h2(r3.z);
        {
            float g0 = __low2float(ha0), g1 = __high2float(ha0), g2 = __low2float(hb0);
            float2 a = fp8x2_to_f32(w00), b = fp8x2_to_f32(w01), c = fp8x2_to_f32(w02);
            ax0 += g0 * a.x + g1 * b.x + g2 * c.x;
            ay0 += g0 * a.y + g1 * b.y + g2 * c.y;
        }
        {
            float g0 = __low2float(ha1), g1 = __high2float(ha1), g2 = __low2float(hb1);
            float2 a = fp8x2_to_f32(w10), b = fp8x2_to_f32(w11), c = fp8x2_to_f32(w12);
            ax1 += g0 * a.x + g1 * b.x + g2 * c.x;
            ay1 += g0 * a.y + g1 * b.y + g2 * c.y;
        }
        {
            float g0 = __low2float(ha2), g1 = __high2float(ha2), g2 = __low2float(hb2);
            float2 a = fp8x2_to_f32(w20), b = fp8x2_to_f32(w21), c = fp8x2_to_f32(w22);
            ax0 += g0 * a.x + g1 * b.x + g2 * c.x;
            ay0 += g0 * a.y + g1 * b.y + g2 * c.y;
        }
        {
            float g0 = __low2float(ha3), g1 = __high2float(ha3), g2 = __low2float(hb3);
            float2 a = fp8x2_to_f32(w30), b = fp8x2_to_f32(w31), c = fp8x2_to_f32(w32);
            ax1 += g0 * a.x + g1 * b.x + g2 * c.x;
            ay1 += g0 * a.y + g1 * b.y + g2 * c.y;
        }
    }
    for (; j < end; ++j) {
        int4 r0 = rec[j];
        __half2 ha0 = int_as_h2(r0.y), hb0 = int_as_h2(r0.z);
        float g0 = __low2float(ha0), g1 = __high2float(ha0), g2 = __low2float(hb0);
        const unsigned short* p0 = reinterpret_cast<const unsigned short*>(
            hw1k + (size_t)r0.x * 192);
        float2 a = fp8x2_to_f32(p0[l]);
        float2 b = fp8x2_to_f32(p0[32 + l]);
        float2 c = fp8x2_to_f32(p0[64 + l]);
        ax0 += g0 * a.x + g1 * b.x + g2 * c.x;
        ay0 += g0 * a.y + g1 * b.y + g2 * c.y;
    }
    float d = fmaxf((float)(end - beg), 1.0f);
    float2 root = __half22float2(
        reinterpret_cast<const __half2*>(hw1r + (size_t)node * 64)[l]);
    float2 bb = reinterpret_cast<const float2*>(b1)[l];
    float v0 = (ax0 + ax1) / d + root.x + bb.x;
    float v1 = (ay0 + ay1) / d + root.y + bb.y;
    float2 o;
    o.x = v0 > 0.f ? v0 : expm1f(v0);
    o.y = v1 > 0.f ? v1 : expm1f(v1);
    reinterpret_cast<float2*>(h2 + (size_t)node * 64)[l] = o;
}

// ---------------------------------------------------------------------------
// agg2: 8 lanes per node, lane owns c = {2l, 2l+1} via half2.
// ---------------------------------------------------------------------------
__global__ __launch_bounds__(256) void agg2_kernel(
    const int4* __restrict__ rec, const int* __restrict__ rowptr,
    const __half* __restrict__ hw2h, const float* __restrict__ b2,
    float* __restrict__ out, int N) {
    int node = (blockIdx.x * 256 + threadIdx.x) >> 3;
    int l = threadIdx.x & 7;
    if (node >= N) return;
    int beg = rowptr[node], end = rowptr[node + 1];
    float ax = 0.f, ay = 0.f;
    for (int j = beg; j < end; ++j) {
        int4 r = rec[j];
        __half2 hb = int_as_h2(r.z), hc = int_as_h2(r.w);
        float g0 = __high2float(hb), g1 = __low2float(hc), g2 = __high2float(hc);
        const __half2* p = reinterpret_cast<const __half2*>(hw2h + (size_t)r.x * 64);
        float2 f0 = __half22float2(p[l]);
        float2 f1 = __half22float2(p[8 + l]);
        float2 f2 = __half22float2(p[16 + l]);
        ax += g0 * f0.x + g1 * f1.x + g2 * f2.x;
        ay += g0 * f0.y + g1 * f1.y + g2 * f2.y;
    }
    float d = fmaxf((float)(end - beg), 1.0f);
    float2 root = __half22float2(
        reinterpret_cast<const __half2*>(hw2h + (size_t)node * 64 + 48)[l]);
    float2 bb = reinterpret_cast<const float2*>(b2)[l];
    float v0 = ax / d + root.x + bb.x;
    float v1 = ay / d + root.y + bb.y;

    float mx = fmaxf(v0, v1);
#pragma unroll
    for (int off = 4; off >= 1; off >>= 1) mx = fmaxf(mx, __shfl_xor(mx, off, 8));
    float s = __expf(v0 - mx) + __expf(v1 - mx);
#pragma unroll
    for (int off = 4; off >= 1; off >>= 1) s += __shfl_xor(s, off, 8);
    float ls = __logf(s);
    float2 o = make_float2(v0 - mx - ls, v1 - mx - ls);
    reinterpret_cast<float2*>(out + (size_t)node * 16)[l] = o;
}

// ---------------------------------------------------------------------------
extern "C" void kernel_launch(void* const* d_in, const int* in_sizes, int n_in,
                              void* d_out, int out_size, void* d_ws, size_t ws_size,
                              hipStream_t stream) {
    const float* x   = (const float*)d_in[0];
    const int*   ei  = (const int*)d_in[1];
    const float* ea  = (const float*)d_in[2];
    const float* g1  = (const float*)d_in[3];
    const float* mu1 = (const float*)d_in[4];
    const float* sg1 = (const float*)d_in[5];
    const float* r1  = (const float*)d_in[6];
    const float* b1  = (const float*)d_in[7];
    const float* g2  = (const float*)d_in[8];
    const float* mu2 = (const float*)d_in[9];
    const float* sg2 = (const float*)d_in[10];
    const float* r2  = (const float*)d_in[11];
    const float* b2  = (const float*)d_in[12];

    const int N = in_sizes[0] / 128;   // 50000
    const int E = in_sizes[2] / 2;     // 800000
    const int nbkt = (N + BKT_SIZE - 1) >> BKT_SHIFT;   // 391

    // Workspace layout
    unsigned char* hw1k = (unsigned char*)d_ws;           // N*192 fp8 (9.6MB)
    __half* hw1r = (__half*)(hw1k + (size_t)N * 192);     // N*64 fp16
    float*  h2   = (float*)(hw1r + (size_t)N * 64);       // N*64 fp32
    __half* hw2h = (__half*)(h2 + (size_t)N * 64);        // N*64 fp16
    int4*   rec  = (int4*)(hw2h + (size_t)N * 64);        // E int4 (12.8MB)
    int4*   staging = rec + E;                            // E int4 (12.8MB)
    __half* Bprep = (__half*)(staging + E);               // 32768 halves
    int*    rowptr  = (int*)(Bprep + 32768);              // N+1
    int*    bcnt    = rowptr + N + 1;                     // nbkt
    int*    bbase   = bcnt + nbkt;                        // nbkt+1
    int*    bcursor = bbase + nbkt + 1;                   // nbkt
    int*    flag    = bcursor + nbkt;                     // 1

    detect_kernel<<<1, 256, 0, stream>>>(ei, flag, bcnt, nbkt);
    bhist_kernel<<<(E + 4095) / 4096, 256, 0, stream>>>(ei, flag, bcnt, E, nbkt);
    bscan_kernel<<<1, 512, 0, stream>>>(bcnt, bbase, bcursor, rowptr + N, nbkt, E);

    pass1_kernel<<<(E + 8191) / 8192, 1024, 0, stream>>>(
        ei, flag, (const float2*)ea, bcursor, staging, E, nbkt);
    pass2_kernel<<<nbkt, 256, 0, stream>>>(
        staging, bbase, mu1, sg1, mu2, sg2, rec, rowptr, N);

    // Layer 1 GEMM (MFMA): x [N,128] @ [g1|root1] -> hw1k fp8 + hw1r fp16
    bprep_kernel<<<128, 256, 0, stream>>>(g1, r1, Bprep);
    gemm1_mfma<<<dim3((N + 63) / 64, 2), 256, 0, stream>>>(x, Bprep, hw1k, hw1r, N);

    agg1_kernel<<<((size_t)N * 32 + 255) / 256, 256, 0, stream>>>(
        rec, rowptr, hw1k, hw1r, b1, h2, N);

    // Layer 2 GEMM: h2 [N,64] @ [g2|root2] [64,64] -> hw2h (fp16)
    gemm_cat<64, 128, 64, 48, 16>
        <<<dim3((N + 127) / 128, 1), 256, 0, stream>>>(h2, g2, r2, hw2h, N);

    agg2_kernel<<<((size_t)N * 8 + 255) / 256, 256, 0, stream>>>(
        rec, rowptr, hw2h, b2, (float*)d_out, N);
}

// Round 12
// 133.064 us; speedup vs baseline: 4.2073x; 1.0215x over previous
//
#include <hip/hip_runtime.h>
#include <hip/hip_fp16.h>

#define EPS 1e-15f
#define BKT_SHIFT 7
#define BKT_SIZE 128
#define NBKT_MAX 512

typedef _Float16 v8h __attribute__((ext_vector_type(8)));
typedef float v4f __attribute__((ext_vector_type(4)));
typedef float v2f __attribute__((ext_vector_type(2)));

#if __has_builtin(__builtin_amdgcn_cvt_pk_f32_fp8) && __has_builtin(__builtin_amdgcn_cvt_pk_fp8_f32)
#define FP8_HW 1
#else
#define FP8_HW 0
#endif

// ---------------------------------------------------------------------------
// fp8 helpers (encode in gemm1, decode in agg1 — matched paths)
// ---------------------------------------------------------------------------
__device__ __forceinline__ unsigned char f32_to_fp8(float v) {
#if FP8_HW
    int r = __builtin_amdgcn_cvt_pk_fp8_f32(v, v, 0, false);
    return (unsigned char)(r & 0xFF);
#else
    __half h = __float2half(v);
    unsigned short u; __builtin_memcpy(&u, &h, 2);
    int s = (u >> 15) << 7;
    int a = (u & 0x7FFF) + 0x40;          // RN on fp8 mantissa bit
    if (a < (9 << 10)) return (unsigned char)s;   // flush tiny to zero-code
    int t = (a >> 7) - 64;
    if (t > 126) t = 126;                 // clamp (avoid NaN code)
    return (unsigned char)(s | t);
#endif
}

__device__ __forceinline__ float2 fp8x2_to_f32(unsigned short w) {
#if FP8_HW
    v2f r = __builtin_amdgcn_cvt_pk_f32_fp8((int)w, false);
    return make_float2(r.x, r.y);
#else
    int b0 = w & 0xFF, b1 = w >> 8;
    unsigned short h0 = (unsigned short)((((b0 & 0x7F) + 64) << 7) | ((b0 & 0x80) << 8));
    unsigned short h1 = (unsigned short)((((b1 & 0x7F) + 64) << 7) | ((b1 & 0x80) << 8));
    __half x0, x1;
    __builtin_memcpy(&x0, &h0, 2);
    __builtin_memcpy(&x1, &h1, 2);
    return make_float2(__half2float(x0), __half2float(x1));
#endif
}

// ---------------------------------------------------------------------------
// Helpers
// ---------------------------------------------------------------------------
__device__ __forceinline__ int load_idx(const int* __restrict__ ei, int is64, int pos) {
    return is64 ? ei[(size_t)2 * pos] : ei[pos];
}

__device__ __forceinline__ int h2_as_int(__half2 h) {
    int w; __builtin_memcpy(&w, &h, 4); return w;
}
__device__ __forceinline__ __half2 int_as_h2(int w) {
    __half2 h; __builtin_memcpy(&h, &w, 4); return h;
}

// Detect int64 vs int32 edge_index; ALSO zeroes bcnt.
__global__ void detect_kernel(const int* __restrict__ ei, int* __restrict__ flag,
                              int* __restrict__ bcnt, int nbkt) {
    __shared__ int any_odd;
    if (threadIdx.x == 0) any_odd = 0;
    __syncthreads();
    for (int u = threadIdx.x; u < nbkt; u += 256) bcnt[u] = 0;
    if (ei[2 * threadIdx.x + 1] != 0) atomicOr(&any_odd, 1);
    __syncthreads();
    if (threadIdx.x == 0) *flag = any_odd ? 0 : 1;
}

// Bucket histogram: LDS-aggregated, 4096 edges/block.
__global__ __launch_bounds__(256) void bhist_kernel(
    const int* __restrict__ ei, const int* __restrict__ flag,
    int* __restrict__ bcnt, int E, int nbkt) {
    __shared__ int cnt[NBKT_MAX];
    int t = threadIdx.x;
    for (int u = t; u < nbkt; u += 256) cnt[u] = 0;
    __syncthreads();
    int is64 = *flag;
    int e0 = blockIdx.x * 4096;
#pragma unroll
    for (int i = 0; i < 16; ++i) {
        int e = e0 + i * 256 + t;
        if (e < E) atomicAdd(&cnt[load_idx(ei, is64, E + e) >> BKT_SHIFT], 1);
    }
    __syncthreads();
    for (int u = t; u < nbkt; u += 256)
        if (cnt[u]) atomicAdd(&bcnt[u], cnt[u]);
}

// Exclusive scan over bcnt[nbkt] (nbkt <= 512); also bbase[nbkt]=E, rowptr[N]=E.
__global__ void bscan_kernel(const int* __restrict__ bcnt, int* __restrict__ bbase,
                             int* __restrict__ bcursor, int* __restrict__ rowptrN,
                             int nbkt, int E) {
    __shared__ int s[512];
    int t = threadIdx.x;
    int v = (t < nbkt) ? bcnt[t] : 0;
    s[t] = v;
    __syncthreads();
    for (int o = 1; o < 512; o <<= 1) {
        int u = (t >= o) ? s[t - o] : 0;
        __syncthreads();
        s[t] += u;
        __syncthreads();
    }
    if (t < nbkt) { int ex = s[t] - v; bbase[t] = ex; bcursor[t] = ex; }
    if (t == 0) { bbase[nbkt] = E; *rowptrN = E; }
}

// ---------------------------------------------------------------------------
// Pass 1: bucket multisplit, 8192 edges per 1024-thread block, two-phase.
// ---------------------------------------------------------------------------
__global__ __launch_bounds__(1024) void pass1_kernel(
    const int* __restrict__ ei, const int* __restrict__ flag,
    const float2* __restrict__ ea, int* __restrict__ bcursor,
    int4* __restrict__ staging, int E, int nbkt) {
    __shared__ int lcnt[NBKT_MAX];
    __shared__ int lcur[NBKT_MAX];
    int t = threadIdx.x;
    if (t < nbkt) lcnt[t] = 0;
    __syncthreads();
    int is64 = *flag;
    int e0 = blockIdx.x * 8192;
    int eend = min(e0 + 8192, E);

    for (int e = e0 + t; e < eend; e += 1024)
        atomicAdd(&lcnt[load_idx(ei, is64, E + e) >> BKT_SHIFT], 1);
    __syncthreads();

    if (t < nbkt) {
        int c = lcnt[t];
        lcur[t] = c ? atomicAdd(&bcursor[t], c) : 0;
    }
    __syncthreads();

    for (int e = e0 + t; e < eend; e += 1024) {
        int src = load_idx(ei, is64, e);
        int dst = load_idx(ei, is64, E + e);
        float2 a = ea[e];
        int pos = atomicAdd(&lcur[dst >> BKT_SHIFT], 1);
        staging[pos] = make_int4(src, dst,
                                 __float_as_int(a.x), __float_as_int(a.y));
    }
}

// ---------------------------------------------------------------------------
// Pass 2: one block per bucket. Derives per-node rowptr; places records.
// ---------------------------------------------------------------------------
__global__ __launch_bounds__(256) void pass2_kernel(
    const int4* __restrict__ staging, const int* __restrict__ bbase,
    const float* __restrict__ mu1, const float* __restrict__ sg1,
    const float* __restrict__ mu2, const float* __restrict__ sg2,
    int4* __restrict__ rec, int* __restrict__ rowptr, int N) {
    __shared__ int lcnt[BKT_SIZE];
    __shared__ int ssc[BKT_SIZE];
    __shared__ int lcur[BKT_SIZE];
    int b = blockIdx.x;
    int node0 = b << BKT_SHIFT;
    int t = threadIdx.x;
    int beg = bbase[b], end = bbase[b + 1];

    if (t < BKT_SIZE) lcnt[t] = 0;
    __syncthreads();
    for (int j = beg + t; j < end; j += 256)
        atomicAdd(&lcnt[staging[j].y & (BKT_SIZE - 1)], 1);
    __syncthreads();
    int v = (t < BKT_SIZE) ? lcnt[t] : 0;
    if (t < BKT_SIZE) ssc[t] = v;
    __syncthreads();
    for (int o = 1; o < BKT_SIZE; o <<= 1) {
        int u = (t < BKT_SIZE && t >= o) ? ssc[t - o] : 0;
        __syncthreads();
        if (t < BKT_SIZE) ssc[t] += u;
        __syncthreads();
    }
    if (t < BKT_SIZE) {
        int excl = beg + ssc[t] - v;
        lcur[t] = excl;
        if (node0 + t < N) rowptr[node0 + t] = excl;
    }
    __syncthreads();

    float m1x[3], m1y[3], i1x[3], i1y[3], m2x[3], m2y[3], i2x[3], i2y[3];
#pragma unroll
    for (int k = 0; k < 3; ++k) {
        m1x[k] = mu1[2 * k]; m1y[k] = mu1[2 * k + 1];
        float s0 = sg1[2 * k], s1 = sg1[2 * k + 1];
        i1x[k] = -0.5f / (EPS + s0 * s0); i1y[k] = -0.5f / (EPS + s1 * s1);
        m2x[k] = mu2[2 * k]; m2y[k] = mu2[2 * k + 1];
        s0 = sg2[2 * k]; s1 = sg2[2 * k + 1];
        i2x[k] = -0.5f / (EPS + s0 * s0); i2y[k] = -0.5f / (EPS + s1 * s1);
    }

    for (int j = beg + t; j < end; j += 256) {
        int4 p = staging[j];
        float ax = __int_as_float(p.z), ay = __int_as_float(p.w);
        float g1v[3], g2v[3];
#pragma unroll
        for (int k = 0; k < 3; ++k) {
            float d0 = ax - m1x[k], d1 = ay - m1y[k];
            g1v[k] = __expf(d0 * d0 * i1x[k] + d1 * d1 * i1y[k]);
            d0 = ax - m2x[k]; d1 = ay - m2y[k];
            g2v[k] = __expf(d0 * d0 * i2x[k] + d1 * d1 * i2y[k]);
        }
        int pos = atomicAdd(&lcur[p.y & (BKT_SIZE - 1)], 1);
        int4 r;
        r.x = p.x;
        r.y = h2_as_int(__floats2half2_rn(g1v[0], g1v[1]));
        r.z = h2_as_int(__floats2half2_rn(g1v[2], g2v[0]));
        r.w = h2_as_int(__floats2half2_rn(g2v[1], g2v[2]));
        rec[pos] = r;
    }
}

// ---------------------------------------------------------------------------
// Bprep: fragment-ordered fp16 copy of W = [g1 | r1]  (128 x 256).
// ---------------------------------------------------------------------------
__global__ void bprep_kernel(const float* __restrict__ g1, const float* __restrict__ r1,
                             __half* __restrict__ Bprep) {
    int gid = blockIdx.x * 256 + threadIdx.x;   // 32768 total
    if (gid >= 32768) return;
    int fi = gid >> 9;
    int lane = (gid >> 3) & 63;
    int i = gid & 7;
    int ks = fi & 3, cb = fi >> 2;
    int k = ks * 32 + (lane >> 4) * 8 + i;
    int c = cb * 16 + (lane & 15);
    float v = (c < 192) ? g1[k * 192 + c] : r1[k * 64 + (c - 192)];
    Bprep[gid] = __float2half(v);
}

// ---------------------------------------------------------------------------
// Layer-1 GEMM via MFMA f16: x [M,128] fp32 -> hw1k fp8 [M,192] + hw1r fp16 [M,64].
// ---------------------------------------------------------------------------
__global__ __launch_bounds__(256) void gemm1_mfma(
    const float* __restrict__ A, const __half* __restrict__ Bprep,
    unsigned char* __restrict__ hw1k, __half* __restrict__ hw1r, int M) {
    __shared__ char a_lds[64 * 256];   // 64 rows x 128 fp16, XOR-swizzled
    int row0 = blockIdx.x * 64;
    int tid = threadIdx.x;
    int wid = tid >> 6, lane = tid & 63;

    const float4* xf4 = reinterpret_cast<const float4*>(A);
#pragma unroll
    for (int j = 0; j < 8; ++j) {
        int g = j * 256 + tid;
        int r = g >> 5, c = g & 31;
        int gr = row0 + r;
        float4 f = (gr < M) ? xf4[(size_t)gr * 32 + c]
                            : make_float4(0.f, 0.f, 0.f, 0.f);
        int2 v;
        v.x = h2_as_int(__floats2half2_rn(f.x, f.y));
        v.y = h2_as_int(__floats2half2_rn(f.z, f.w));
        int byte = r * 256 + c * 8;
        byte ^= (r & 7) << 4;
        *reinterpret_cast<int2*>(&a_lds[byte]) = v;
    }

    v8h bf[2][4];   // [cf][ks]
#pragma unroll
    for (int cf = 0; cf < 2; ++cf)
#pragma unroll
        for (int ks = 0; ks < 4; ++ks) {
            int cb = blockIdx.y * 8 + wid * 2 + cf;
            int fi = cb * 4 + ks;
            bf[cf][ks] = *reinterpret_cast<const v8h*>(Bprep + (size_t)fi * 512 + lane * 8);
        }

    __syncthreads();

    v4f acc[4][2] = {};
#pragma unroll
    for (int ks = 0; ks < 4; ++ks) {
        v8h af[4];
#pragma unroll
        for (int rf = 0; rf < 4; ++rf) {
            int r = rf * 16 + (lane & 15);
            int byte = r * 256 + ks * 64 + (lane >> 4) * 16;
            byte ^= (r & 7) << 4;
            af[rf] = *reinterpret_cast<const v8h*>(&a_lds[byte]);
        }
#pragma unroll
        for (int rf = 0; rf < 4; ++rf)
#pragma unroll
            for (int cf = 0; cf < 2; ++cf)
                acc[rf][cf] = __builtin_amdgcn_mfma_f32_16x16x32_f16(
                    af[rf], bf[cf][ks], acc[rf][cf], 0, 0, 0);
    }

#pragma unroll
    for (int rf = 0; rf < 4; ++rf)
#pragma unroll
        for (int cf = 0; cf < 2; ++cf) {
            int gc = blockIdx.y * 128 + wid * 32 + cf * 16 + (lane & 15);
#pragma unroll
            for (int i = 0; i < 4; ++i) {
                int gr = row0 + rf * 16 + (lane >> 4) * 4 + i;
                if (gr < M) {
                    float val = acc[rf][cf][i];
                    if (gc < 192)
                        hw1k[(size_t)gr * 192 + gc] = f32_to_fp8(val);
                    else
                        hw1r[(size_t)gr * 64 + (gc - 192)] = __float2half(val);
                }
            }
        }
}

// ---------------------------------------------------------------------------
// agg1 (fused with layer-2 GEMM): 32 lanes per node, 8 nodes per 256-thr block.
// Gather-aggregate from fp8 table -> ELU h2 row in LDS -> 64x64 matvec with
// LDS-staged [g2|r2] -> hw2h fp16. h2 never touches global memory.
// ---------------------------------------------------------------------------
__global__ __launch_bounds__(256) void agg1_fused(
    const int4* __restrict__ rec, const int* __restrict__ rowptr,
    const unsigned char* __restrict__ hw1k, const __half* __restrict__ hw1r,
    const float* __restrict__ b1, const float* __restrict__ g2,
    const float* __restrict__ r2, __half* __restrict__ hw2h, int N) {
    __shared__ float Wlds[64][64];   // [k][c]: c<48 from g2, c>=48 from r2
    __shared__ float h2s[8][64];
    int t = threadIdx.x;

    // Stage layer-2 weights (L2-hot, 4096 floats)
    for (int i = t; i < 4096; i += 256) {
        int k = i >> 6, c = i & 63;
        Wlds[k][c] = (c < 48) ? g2[k * 48 + c] : r2[k * 16 + (c - 48)];
    }

    int node = (blockIdx.x * 256 + t) >> 5;
    int nl = (t >> 5) & 7;          // node slot in block
    int l = t & 31;
    bool active = node < N;

    float ax0 = 0.f, ay0 = 0.f, ax1 = 0.f, ay1 = 0.f;
    int beg = 0, end = 0;
    if (active) { beg = rowptr[node]; end = rowptr[node + 1]; }
    int j = beg;
    for (; j + 3 < end; j += 4) {
        int4 r0 = rec[j], r1 = rec[j + 1], r2v = rec[j + 2], r3 = rec[j + 3];
        const unsigned short* p0 = reinterpret_cast<const unsigned short*>(
            hw1k + (size_t)r0.x * 192);
        const unsigned short* p1 = reinterpret_cast<const unsigned short*>(
            hw1k + (size_t)r1.x * 192);
        const unsigned short* p2 = reinterpret_cast<const unsigned short*>(
            hw1k + (size_t)r2v.x * 192);
        const unsigned short* p3 = reinterpret_cast<const unsigned short*>(
            hw1k + (size_t)r3.x * 192);
        unsigned short w00 = p0[l], w01 = p0[32 + l], w02 = p0[64 + l];
        unsigned short w10 = p1[l], w11 = p1[32 + l], w12 = p1[64 + l];
        unsigned short w20 = p2[l], w21 = p2[32 + l], w22 = p2[64 + l];
        unsigned short w30 = p3[l], w31 = p3[32 + l], w32 = p3[64 + l];
        __half2 ha0 = int_as_h2(r0.y), hb0 = int_as_h2(r0.z);
        __half2 ha1 = int_as_h2(r1.y), hb1 = int_as_h2(r1.z);
        __half2 ha2 = int_as_h2(r2v.y), hb2 = int_as_h2(r2v.z);
        __half2 ha3 = int_as_h2(r3.y), hb3 = int_as_h2(r3.z);
        {
            float g0 = __low2float(ha0), g1 = __high2float(ha0), gg2 = __low2float(hb0);
            float2 a = fp8x2_to_f32(w00), b = fp8x2_to_f32(w01), c = fp8x2_to_f32(w02);
            ax0 += g0 * a.x + g1 * b.x + gg2 * c.x;
            ay0 += g0 * a.y + g1 * b.y + gg2 * c.y;
        }
        {
            float g0 = __low2float(ha1), g1 = __high2float(ha1), gg2 = __low2float(hb1);
            float2 a = fp8x2_to_f32(w10), b = fp8x2_to_f32(w11), c = fp8x2_to_f32(w12);
            ax1 += g0 * a.x + g1 * b.x + gg2 * c.x;
            ay1 += g0 * a.y + g1 * b.y + gg2 * c.y;
        }
        {
            float g0 = __low2float(ha2), g1 = __high2float(ha2), gg2 = __low2float(hb2);
            float2 a = fp8x2_to_f32(w20), b = fp8x2_to_f32(w21), c = fp8x2_to_f32(w22);
            ax0 += g0 * a.x + g1 * b.x + gg2 * c.x;
            ay0 += g0 * a.y + g1 * b.y + gg2 * c.y;
        }
        {
            float g0 = __low2float(ha3), g1 = __high2float(ha3), gg2 = __low2float(hb3);
            float2 a = fp8x2_to_f32(w30), b = fp8x2_to_f32(w31), c = fp8x2_to_f32(w32);
            ax1 += g0 * a.x + g1 * b.x + gg2 * c.x;
            ay1 += g0 * a.y + g1 * b.y + gg2 * c.y;
        }
    }
    for (; j < end; ++j) {
        int4 r0 = rec[j];
        __half2 ha0 = int_as_h2(r0.y), hb0 = int_as_h2(r0.z);
        float g0 = __low2float(ha0), g1 = __high2float(ha0), gg2 = __low2float(hb0);
        const unsigned short* p0 = reinterpret_cast<const unsigned short*>(
            hw1k + (size_t)r0.x * 192);
        float2 a = fp8x2_to_f32(p0[l]);
        float2 b = fp8x2_to_f32(p0[32 + l]);
        float2 c = fp8x2_to_f32(p0[64 + l]);
        ax0 += g0 * a.x + g1 * b.x + gg2 * c.x;
        ay0 += g0 * a.y + g1 * b.y + gg2 * c.y;
    }
    if (active) {
        float d = fmaxf((float)(end - beg), 1.0f);
        float2 root = __half22float2(
            reinterpret_cast<const __half2*>(hw1r + (size_t)node * 64)[l]);
        float2 bb = reinterpret_cast<const float2*>(b1)[l];
        float v0 = (ax0 + ax1) / d + root.x + bb.x;
        float v1 = (ay0 + ay1) / d + root.y + bb.y;
        h2s[nl][2 * l]     = v0 > 0.f ? v0 : expm1f(v0);
        h2s[nl][2 * l + 1] = v1 > 0.f ? v1 : expm1f(v1);
    }
    __syncthreads();

    // Layer-2 matvec: thread computes cols {2l, 2l+1} of its node slot.
    if (active) {
        float acc0 = 0.f, acc1 = 0.f;
#pragma unroll 8
        for (int k = 0; k < 64; ++k) {
            float hv = h2s[nl][k];                       // LDS broadcast
            float2 w = *reinterpret_cast<const float2*>(&Wlds[k][2 * l]);
            acc0 += hv * w.x;
            acc1 += hv * w.y;
        }
        reinterpret_cast<__half2*>(hw2h)[(size_t)node * 32 + l] =
            __floats2half2_rn(acc0, acc1);
    }
}

// ---------------------------------------------------------------------------
// agg2: 8 lanes per node, lane owns c = {2l, 2l+1} via half2.
// ---------------------------------------------------------------------------
__global__ __launch_bounds__(256) void agg2_kernel(
    const int4* __restrict__ rec, const int* __restrict__ rowptr,
    const __half* __restrict__ hw2h, const float* __restrict__ b2,
    float* __restrict__ out, int N) {
    int node = (blockIdx.x * 256 + threadIdx.x) >> 3;
    int l = threadIdx.x & 7;
    if (node >= N) return;
    int beg = rowptr[node], end = rowptr[node + 1];
    float ax = 0.f, ay = 0.f;
    for (int j = beg; j < end; ++j) {
        int4 r = rec[j];
        __half2 hb = int_as_h2(r.z), hc = int_as_h2(r.w);
        float g0 = __high2float(hb), g1 = __low2float(hc), g2 = __high2float(hc);
        const __half2* p = reinterpret_cast<const __half2*>(hw2h + (size_t)r.x * 64);
        float2 f0 = __half22float2(p[l]);
        float2 f1 = __half22float2(p[8 + l]);
        float2 f2 = __half22float2(p[16 + l]);
        ax += g0 * f0.x + g1 * f1.x + g2 * f2.x;
        ay += g0 * f0.y + g1 * f1.y + g2 * f2.y;
    }
    float d = fmaxf((float)(end - beg), 1.0f);
    float2 root = __half22float2(
        reinterpret_cast<const __half2*>(hw2h + (size_t)node * 64 + 48)[l]);
    float2 bb = reinterpret_cast<const float2*>(b2)[l];
    float v0 = ax / d + root.x + bb.x;
    float v1 = ay / d + root.y + bb.y;

    float mx = fmaxf(v0, v1);
#pragma unroll
    for (int off = 4; off >= 1; off >>= 1) mx = fmaxf(mx, __shfl_xor(mx, off, 8));
    float s = __expf(v0 - mx) + __expf(v1 - mx);
#pragma unroll
    for (int off = 4; off >= 1; off >>= 1) s += __shfl_xor(s, off, 8);
    float ls = __logf(s);
    float2 o = make_float2(v0 - mx - ls, v1 - mx - ls);
    reinterpret_cast<float2*>(out + (size_t)node * 16)[l] = o;
}

// ---------------------------------------------------------------------------
extern "C" void kernel_launch(void* const* d_in, const int* in_sizes, int n_in,
                              void* d_out, int out_size, void* d_ws, size_t ws_size,
                              hipStream_t stream) {
    const float* x   = (const float*)d_in[0];
    const int*   ei  = (const int*)d_in[1];
    const float* ea  = (const float*)d_in[2];
    const float* g1  = (const float*)d_in[3];
    const float* mu1 = (const float*)d_in[4];
    const float* sg1 = (const float*)d_in[5];
    const float* r1  = (const float*)d_in[6];
    const float* b1  = (const float*)d_in[7];
    const float* g2  = (const float*)d_in[8];
    const float* mu2 = (const float*)d_in[9];
    const float* sg2 = (const float*)d_in[10];
    const float* r2  = (const float*)d_in[11];
    const float* b2  = (const float*)d_in[12];

    const int N = in_sizes[0] / 128;   // 50000
    const int E = in_sizes[2] / 2;     // 800000
    const int nbkt = (N + BKT_SIZE - 1) >> BKT_SHIFT;   // 391

    // Workspace layout
    unsigned char* hw1k = (unsigned char*)d_ws;           // N*192 fp8 (9.6MB)
    __half* hw1r = (__half*)(hw1k + (size_t)N * 192);     // N*64 fp16
    __half* hw2h = (__half*)(hw1r + (size_t)N * 64);      // N*64 fp16
    int4*   rec  = (int4*)(hw2h + (size_t)N * 64);        // E int4 (12.8MB)
    int4*   staging = rec + E;                            // E int4 (12.8MB)
    __half* Bprep = (__half*)(staging + E);               // 32768 halves
    int*    rowptr  = (int*)(Bprep + 32768);              // N+1
    int*    bcnt    = rowptr + N + 1;                     // nbkt
    int*    bbase   = bcnt + nbkt;                        // nbkt+1
    int*    bcursor = bbase + nbkt + 1;                   // nbkt
    int*    flag    = bcursor + nbkt;                     // 1

    detect_kernel<<<1, 256, 0, stream>>>(ei, flag, bcnt, nbkt);
    bhist_kernel<<<(E + 4095) / 4096, 256, 0, stream>>>(ei, flag, bcnt, E, nbkt);
    bscan_kernel<<<1, 512, 0, stream>>>(bcnt, bbase, bcursor, rowptr + N, nbkt, E);

    pass1_kernel<<<(E + 8191) / 8192, 1024, 0, stream>>>(
        ei, flag, (const float2*)ea, bcursor, staging, E, nbkt);
    pass2_kernel<<<nbkt, 256, 0, stream>>>(
        staging, bbase, mu1, sg1, mu2, sg2, rec, rowptr, N);

    // Layer 1 GEMM (MFMA): x [N,128] @ [g1|root1] -> hw1k fp8 + hw1r fp16
    bprep_kernel<<<128, 256, 0, stream>>>(g1, r1, Bprep);
    gemm1_mfma<<<dim3((N + 63) / 64, 2), 256, 0, stream>>>(x, Bprep, hw1k, hw1r, N);

    // agg1 + layer-2 GEMM fused: -> hw2h
    agg1_fused<<<((size_t)N * 32 + 255) / 256, 256, 0, stream>>>(
        rec, rowptr, hw1k, hw1r, b1, g2, r2, hw2h, N);

    agg2_kernel<<<((size_t)N * 8 + 255) / 256, 256, 0, stream>>>(
        rec, rowptr, hw2h, b2, (float*)d_out, N);
}